// Round 2
// baseline (1355.478 us; speedup 1.0000x reference)
//
#include <hip/hip_runtime.h>

#define NDIM 160
#define MROWS (NDIM*NDIM)          // 25600
#define NC1 1600                   // padded projection output cols
#define QK_SCALE 0.17677669529663687f

typedef __attribute__((ext_vector_type(8))) short bhalf8;
typedef __attribute__((ext_vector_type(4))) float floatx4;

static __device__ __forceinline__ short f2bf(float f) {
  unsigned int u = __builtin_bit_cast(unsigned int, f);
  u = (u + 0x7FFFu + ((u >> 16) & 1u)) >> 16;
  return (short)(u & 0xFFFFu);
}

// ---------------- prep: pack transposed bf16 weights ----------------
__global__ __launch_bounds__(256) void prep_kernel(
    const float* __restrict__ Wqkv_in, const float* __restrict__ bqkv_in,
    const float* __restrict__ Weg_in, const float* __restrict__ beg_in,
    const float* __restrict__ Wqkv_out, const float* __restrict__ bqkv_out,
    const float* __restrict__ Weg_out, const float* __restrict__ beg_out,
    const float* __restrict__ Wo,
    short* __restrict__ WcT, float* __restrict__ biasc, short* __restrict__ WoT) {
  int idx = blockIdx.x * 256 + threadIdx.x;
  if (idx < NC1 * 256) {
    int n = idx >> 8, k = idx & 255;
    float w = 0.f;
    if (n < 768)        { w = Wqkv_in[k*768 + n];          if (n < 256) w *= QK_SCALE; }
    else if (n < 1536)  { int cc = n - 768; w = Wqkv_out[k*768 + cc]; if (cc < 256) w *= QK_SCALE; }
    else if (n < 1552)  { w = Weg_in[k*16 + (n - 1536)]; }
    else if (n < 1568)  { w = Weg_out[k*16 + (n - 1552)]; }
    WcT[n*256 + k] = f2bf(w);
    if (k == 0) {
      float bb = 0.f;
      if (n < 768)        { bb = bqkv_in[n];           if (n < 256) bb *= QK_SCALE; }
      else if (n < 1536)  { int cc = n - 768; bb = bqkv_out[cc]; if (cc < 256) bb *= QK_SCALE; }
      else if (n < 1552)  bb = beg_in[n - 1536];
      else if (n < 1568)  bb = beg_out[n - 1552];
      biasc[n] = bb;
    }
  } else {
    int i2 = idx - NC1 * 256;       // 0 .. 131071  -> WoT[256][512]
    int c = i2 >> 9, cc = i2 & 511;
    WoT[c*512 + cc] = f2bf(Wo[cc*256 + c]);
  }
}

// ---------------- layernorm -> bf16 ----------------
__global__ __launch_bounds__(256) void ln_kernel(
    const float* __restrict__ e, const float* __restrict__ g,
    const float* __restrict__ b, short* __restrict__ eln) {
  int row = blockIdx.x;
  int t = threadIdx.x;
  float x = e[row*256 + t];
  float s = x;
#pragma unroll
  for (int o = 1; o < 64; o <<= 1) s += __shfl_xor(s, o, 64);
  __shared__ float red[8];
  int wave = t >> 6, lane = t & 63;
  if (lane == 0) red[wave] = s;
  __syncthreads();
  float mu = (red[0] + red[1] + red[2] + red[3]) * (1.f/256.f);
  float dx = x - mu;
  float q = dx * dx;
#pragma unroll
  for (int o = 1; o < 64; o <<= 1) q += __shfl_xor(q, o, 64);
  if (lane == 0) red[4 + wave] = q;
  __syncthreads();
  float var = (red[4] + red[5] + red[6] + red[7]) * (1.f/256.f);
  float y = dx * rsqrtf(var + 1e-5f) * g[t] + b[t];
  eln[row*256 + t] = f2bf(y);
}

// ---------------- QKV + EG projection GEMM, scattered epilogue ----------------
// eln[25600][256] @ WcT^T -> 1600 cols.  64x64 tiles, 4 waves of 32x32.
__global__ __launch_bounds__(256) void qkv_gemm_kernel(
    const short* __restrict__ eln, const short* __restrict__ WcT,
    const float* __restrict__ biasc,
    short* __restrict__ Qin, short* __restrict__ Kin, short* __restrict__ Vin,
    short* __restrict__ Qout, short* __restrict__ Kout, short* __restrict__ Vout,
    float* __restrict__ Ein, float* __restrict__ Gin,
    float* __restrict__ Eout, float* __restrict__ Gout) {
  int bm = blockIdx.x * 64, bn = blockIdx.y * 64;
  int wave = threadIdx.x >> 6, lane = threadIdx.x & 63;
  int wm = bm + (wave >> 1) * 32, wn = bn + (wave & 1) * 32;
  int lr = lane & 15, lg = lane >> 4;
  floatx4 acc[2][2] = {};
  const short* arow0 = eln + (wm + lr) * 256;
  const short* arow1 = eln + (wm + 16 + lr) * 256;
  const short* brow0 = WcT + (wn + lr) * 256;
  const short* brow1 = WcT + (wn + 16 + lr) * 256;
  for (int kk = 0; kk < 256; kk += 32) {
    int ko = kk + lg * 8;
    bhalf8 a0 = *(const bhalf8*)(arow0 + ko);
    bhalf8 a1 = *(const bhalf8*)(arow1 + ko);
    bhalf8 b0 = *(const bhalf8*)(brow0 + ko);
    bhalf8 b1 = *(const bhalf8*)(brow1 + ko);
    acc[0][0] = __builtin_amdgcn_mfma_f32_16x16x32_bf16(a0, b0, acc[0][0], 0, 0, 0);
    acc[0][1] = __builtin_amdgcn_mfma_f32_16x16x32_bf16(a0, b1, acc[0][1], 0, 0, 0);
    acc[1][0] = __builtin_amdgcn_mfma_f32_16x16x32_bf16(a1, b0, acc[1][0], 0, 0, 0);
    acc[1][1] = __builtin_amdgcn_mfma_f32_16x16x32_bf16(a1, b1, acc[1][1], 0, 0, 0);
  }
#pragma unroll
  for (int i = 0; i < 2; i++)
#pragma unroll
    for (int jf = 0; jf < 2; jf++)
#pragma unroll
      for (int r = 0; r < 4; r++) {
        int m = wm + i*16 + lg*4 + r;
        int n = wn + jf*16 + lr;
        float v = acc[i][jf][r] + biasc[n];
        int ai = m / 160, bj = m % 160;   // (first, second) spatial index
        if (n < 1536) {
          int br = n >= 768;
          int cc = br ? n - 768 : n;
          int part = cc >> 8;
          int c = cc & 255;
          int d = c >> 3, h = c & 7;      // channel c -> (d, h), h fast
          short bv = f2bf(v);
          if (!br) {
            if (part == 0)      Qin[((bj*8 + h)*160 + ai)*32 + d] = bv;   // [j][h][i][d]
            else if (part == 1) Kin[((ai*8 + h)*160 + bj)*32 + d] = bv;   // [j][h][k][d]
            else                Vin[((ai*8 + h)*32 + d)*160 + bj] = bv;   // [j][h][d][k]
          } else {
            if (part == 0)      Qout[((bj*8 + h)*160 + ai)*32 + d] = bv;  // [j][h][i][d]
            else if (part == 1) Kout[((bj*8 + h)*160 + ai)*32 + d] = bv;  // [j][h][k][d]
            else                Vout[((bj*8 + h)*32 + d)*160 + ai] = bv;  // [j][h][d][k]
          }
        } else if (n < 1552) {
          int hh = n - 1536;
          float* dst = (hh < 8) ? Ein : Gin;
          dst[(ai*160 + bj)*8 + (hh & 7)] = v;    // [i][k][h]
        } else if (n < 1568) {
          int hh = n - 1552;
          float* dst = (hh < 8) ? Eout : Gout;
          dst[(ai*160 + bj)*8 + (hh & 7)] = v;    // [k][i][h]
        }
      }
}

// ---------------- fused attention: one block per (j, h, branch) ----------------
__global__ __launch_bounds__(256) void attn_kernel(
    const short* __restrict__ Qin, const short* __restrict__ Kin, const short* __restrict__ Vin,
    const short* __restrict__ Qout, const short* __restrict__ Kout, const short* __restrict__ Vout,
    const float* __restrict__ Ein, const float* __restrict__ Gin,
    const float* __restrict__ Eout, const float* __restrict__ Gout,
    const float* __restrict__ mask, short* __restrict__ Va) {
  int j = blockIdx.x, h = blockIdx.y, br = blockIdx.z;
  const short* Qg = (br ? Qout : Qin) + (j*8 + h) * 5120;
  const short* Kg = (br ? Kout : Kin) + (j*8 + h) * 5120;
  const short* Vg = (br ? Vout : Vin) + (j*8 + h) * 5120;
  const float* E = br ? Eout : Ein;
  const float* G = br ? Gout : Gin;
  __shared__ short Qs[5120], Ks[5120], Vs[5120];
  __shared__ short Ps[4][2560];
  for (int t = threadIdx.x; t < 640; t += 256) {
    ((bhalf8*)Qs)[t] = ((const bhalf8*)Qg)[t];
    ((bhalf8*)Ks)[t] = ((const bhalf8*)Kg)[t];
    ((bhalf8*)Vs)[t] = ((const bhalf8*)Vg)[t];
  }
  __syncthreads();
  int wave = threadIdx.x >> 6, lane = threadIdx.x & 63;
  int lr = lane & 15, lg = lane >> 4;
  const floatx4 zero = {0.f, 0.f, 0.f, 0.f};
  for (int qt = wave; qt < 10; qt += 4) {
    bhalf8 aq = *(const bhalf8*)(Qs + (qt*16 + lr)*32 + lg*8);
    floatx4 s[10];
#pragma unroll
    for (int kt = 0; kt < 10; kt++) {
      bhalf8 bk = *(const bhalf8*)(Ks + (kt*16 + lr)*32 + lg*8);
      s[kt] = __builtin_amdgcn_mfma_f32_16x16x32_bf16(aq, bk, zero, 0, 0, 0);
    }
    // D-frag: col(key) = lr + 16*kt, row(query) = qt*16 + lg*4 + r
    float mx[4] = {-1e30f, -1e30f, -1e30f, -1e30f};
#pragma unroll
    for (int kt = 0; kt < 10; kt++) {
      int k = kt*16 + lr;
#pragma unroll
      for (int r = 0; r < 4; r++) {
        int i = qt*16 + lg*4 + r;
        int eidx = br ? ((k*160 + i)*8 + h) : ((i*160 + k)*8 + h);
        float val = s[kt][r] + E[eidx] + mask[eidx];
        s[kt][r] = val;
        mx[r] = fmaxf(mx[r], val);
      }
    }
#pragma unroll
    for (int r = 0; r < 4; r++) {
#pragma unroll
      for (int o = 1; o < 16; o <<= 1) mx[r] = fmaxf(mx[r], __shfl_xor(mx[r], o, 64));
    }
    float sm[4] = {0.f, 0.f, 0.f, 0.f};
#pragma unroll
    for (int kt = 0; kt < 10; kt++)
#pragma unroll
      for (int r = 0; r < 4; r++) {
        float p = __expf(s[kt][r] - mx[r]);
        s[kt][r] = p;
        sm[r] += p;
      }
#pragma unroll
    for (int r = 0; r < 4; r++) {
#pragma unroll
      for (int o = 1; o < 16; o <<= 1) sm[r] += __shfl_xor(sm[r], o, 64);
      sm[r] = 1.f / sm[r];
    }
#pragma unroll
    for (int kt = 0; kt < 10; kt++) {
      int k = kt*16 + lr;
#pragma unroll
      for (int r = 0; r < 4; r++) {
        int i = qt*16 + lg*4 + r;
        int eidx = br ? ((k*160 + i)*8 + h) : ((i*160 + k)*8 + h);
        float gv = G[eidx] + mask[eidx];
        float gate = 1.f / (1.f + __expf(-gv));
        float aval = s[kt][r] * sm[r] * gate;
        Ps[wave][(lg*4 + r)*160 + k] = f2bf(aval);
      }
    }
    floatx4 accv[2] = {zero, zero};
#pragma unroll
    for (int kc = 0; kc < 5; kc++) {
      bhalf8 ap = *(const bhalf8*)(&Ps[wave][lr*160 + kc*32 + lg*8]);
#pragma unroll
      for (int dt = 0; dt < 2; dt++) {
        bhalf8 bv = *(const bhalf8*)(Vs + (dt*16 + lr)*160 + kc*32 + lg*8);
        accv[dt] = __builtin_amdgcn_mfma_f32_16x16x32_bf16(ap, bv, accv[dt], 0, 0, 0);
      }
    }
    int hh = br*8 + h;
#pragma unroll
    for (int dt = 0; dt < 2; dt++)
#pragma unroll
      for (int r = 0; r < 4; r++) {
        int i = qt*16 + lg*4 + r;
        int d = dt*16 + lr;
        Va[(i*160 + j)*512 + d*16 + hh] = f2bf(accv[dt][r]);   // [(i,j)][d*16+hh]
      }
  }
}

// ---------------- output projection GEMM ----------------
__global__ __launch_bounds__(256) void out_gemm_kernel(
    const short* __restrict__ Va, const short* __restrict__ WoT,
    const float* __restrict__ bo, float* __restrict__ out) {
  int bm = blockIdx.x * 64, bn = blockIdx.y * 64;
  int wave = threadIdx.x >> 6, lane = threadIdx.x & 63;
  int wm = bm + (wave >> 1) * 32, wn = bn + (wave & 1) * 32;
  int lr = lane & 15, lg = lane >> 4;
  floatx4 acc[2][2] = {};
  const short* arow0 = Va + (wm + lr) * 512;
  const short* arow1 = Va + (wm + 16 + lr) * 512;
  const short* brow0 = WoT + (wn + lr) * 512;
  const short* brow1 = WoT + (wn + 16 + lr) * 512;
  for (int kk = 0; kk < 512; kk += 32) {
    int ko = kk + lg * 8;
    bhalf8 a0 = *(const bhalf8*)(arow0 + ko);
    bhalf8 a1 = *(const bhalf8*)(arow1 + ko);
    bhalf8 b0 = *(const bhalf8*)(brow0 + ko);
    bhalf8 b1 = *(const bhalf8*)(brow1 + ko);
    acc[0][0] = __builtin_amdgcn_mfma_f32_16x16x32_bf16(a0, b0, acc[0][0], 0, 0, 0);
    acc[0][1] = __builtin_amdgcn_mfma_f32_16x16x32_bf16(a0, b1, acc[0][1], 0, 0, 0);
    acc[1][0] = __builtin_amdgcn_mfma_f32_16x16x32_bf16(a1, b0, acc[1][0], 0, 0, 0);
    acc[1][1] = __builtin_amdgcn_mfma_f32_16x16x32_bf16(a1, b1, acc[1][1], 0, 0, 0);
  }
#pragma unroll
  for (int i = 0; i < 2; i++)
#pragma unroll
    for (int jf = 0; jf < 2; jf++)
#pragma unroll
      for (int r = 0; r < 4; r++) {
        int m = wm + i*16 + lg*4 + r;
        int n = wn + jf*16 + lr;
        out[m*256 + n] = acc[i][jf][r] + bo[n];
      }
}

extern "C" void kernel_launch(void* const* d_in, const int* in_sizes, int n_in,
                              void* d_out, int out_size, void* d_ws, size_t ws_size,
                              hipStream_t stream) {
  const float* e        = (const float*)d_in[0];
  const float* mask     = (const float*)d_in[1];
  const float* ln_g     = (const float*)d_in[2];
  const float* ln_b     = (const float*)d_in[3];
  const float* Wqkv_in  = (const float*)d_in[4];
  const float* bqkv_in  = (const float*)d_in[5];
  const float* Weg_in   = (const float*)d_in[6];
  const float* beg_in   = (const float*)d_in[7];
  const float* Wqkv_out = (const float*)d_in[8];
  const float* bqkv_out = (const float*)d_in[9];
  const float* Weg_out  = (const float*)d_in[10];
  const float* beg_out  = (const float*)d_in[11];
  const float* Wo       = (const float*)d_in[12];
  const float* bo       = (const float*)d_in[13];
  float* out = (float*)d_out;

  char* ws = (char*)d_ws;
  size_t off = 0;
  auto alloc = [&](size_t bytes) -> void* {
    void* p = ws + off;
    off += (bytes + 255) & ~(size_t)255;
    return p;
  };
  short* eln   = (short*)alloc((size_t)MROWS*256*2);     // 13.1 MB
  short* WcT   = (short*)alloc((size_t)NC1*256*2);
  float* biasc = (float*)alloc((size_t)NC1*4);
  short* WoT   = (short*)alloc((size_t)256*512*2);
  short* Qin   = (short*)alloc((size_t)160*8*160*32*2);  // 13.1 MB each
  short* Kin   = (short*)alloc((size_t)160*8*160*32*2);
  short* Vin   = (short*)alloc((size_t)160*8*160*32*2);
  short* Qout  = (short*)alloc((size_t)160*8*160*32*2);
  short* Kout  = (short*)alloc((size_t)160*8*160*32*2);
  short* Vout  = (short*)alloc((size_t)160*8*160*32*2);
  float* Ein   = (float*)alloc((size_t)160*160*8*4);
  float* Gin   = (float*)alloc((size_t)160*160*8*4);
  float* Eout  = (float*)alloc((size_t)160*160*8*4);
  float* Gout  = (float*)alloc((size_t)160*160*8*4);
  short* Vabuf = (short*)alloc((size_t)MROWS*512*2);     // 26.2 MB

  prep_kernel<<<2112, 256, 0, stream>>>(Wqkv_in, bqkv_in, Weg_in, beg_in,
                                        Wqkv_out, bqkv_out, Weg_out, beg_out,
                                        Wo, WcT, biasc, WoT);
  ln_kernel<<<MROWS, 256, 0, stream>>>(e, ln_g, ln_b, eln);
  qkv_gemm_kernel<<<dim3(400, 25), 256, 0, stream>>>(eln, WcT, biasc,
      Qin, Kin, Vin, Qout, Kout, Vout, Ein, Gin, Eout, Gout);
  attn_kernel<<<dim3(160, 8, 2), 256, 0, stream>>>(Qin, Kin, Vin, Qout, Kout, Vout,
      Ein, Gin, Eout, Gout, mask, Vabuf);
  out_gemm_kernel<<<dim3(400, 4), 256, 0, stream>>>(Vabuf, WoT, bo, out);
}

// Round 3
// 448.217 us; speedup vs baseline: 3.0242x; 3.0242x over previous
//
#include <hip/hip_runtime.h>

#define NDIM 160
#define MROWS (NDIM*NDIM)          // 25600
#define NC1 1600                   // padded projection output cols
#define QK_SCALE 0.17677669529663687f

typedef __attribute__((ext_vector_type(8))) short bhalf8;
typedef __attribute__((ext_vector_type(4))) float floatx4;

static __device__ __forceinline__ short f2bf(float f) {
  unsigned int u = __builtin_bit_cast(unsigned int, f);
  u = (u + 0x7FFFu + ((u >> 16) & 1u)) >> 16;
  return (short)(u & 0xFFFFu);
}

// ---------------- prep: pack transposed bf16 weights ----------------
__global__ __launch_bounds__(256) void prep_kernel(
    const float* __restrict__ Wqkv_in, const float* __restrict__ bqkv_in,
    const float* __restrict__ Weg_in, const float* __restrict__ beg_in,
    const float* __restrict__ Wqkv_out, const float* __restrict__ bqkv_out,
    const float* __restrict__ Weg_out, const float* __restrict__ beg_out,
    const float* __restrict__ Wo,
    short* __restrict__ WcT, float* __restrict__ biasc, short* __restrict__ WoT) {
  int idx = blockIdx.x * 256 + threadIdx.x;
  if (idx < NC1 * 256) {
    int n = idx >> 8, k = idx & 255;
    float w = 0.f;
    if (n < 768)        { w = Wqkv_in[k*768 + n];          if (n < 256) w *= QK_SCALE; }
    else if (n < 1536)  { int cc = n - 768; w = Wqkv_out[k*768 + cc]; if (cc < 256) w *= QK_SCALE; }
    else if (n < 1552)  { w = Weg_in[k*16 + (n - 1536)]; }
    else if (n < 1568)  { w = Weg_out[k*16 + (n - 1552)]; }
    WcT[n*256 + k] = f2bf(w);
    if (k == 0) {
      float bb = 0.f;
      if (n < 768)        { bb = bqkv_in[n];           if (n < 256) bb *= QK_SCALE; }
      else if (n < 1536)  { int cc = n - 768; bb = bqkv_out[cc]; if (cc < 256) bb *= QK_SCALE; }
      else if (n < 1552)  bb = beg_in[n - 1536];
      else if (n < 1568)  bb = beg_out[n - 1552];
      biasc[n] = bb;
    }
  } else {
    int i2 = idx - NC1 * 256;       // 0 .. 131071  -> WoT[256][512]
    int c = i2 >> 9, cc = i2 & 511;
    // Va slot cc = hh*32 + d ; original channel ch = d*16 + hh
    int ch = (cc & 31) * 16 + (cc >> 5);
    WoT[c*512 + cc] = f2bf(Wo[ch*256 + c]);
  }
}

// ---------------- layernorm -> bf16 ----------------
__global__ __launch_bounds__(256) void ln_kernel(
    const float* __restrict__ e, const float* __restrict__ g,
    const float* __restrict__ b, short* __restrict__ eln) {
  int row = blockIdx.x;
  int t = threadIdx.x;
  float x = e[row*256 + t];
  float s = x;
#pragma unroll
  for (int o = 1; o < 64; o <<= 1) s += __shfl_xor(s, o, 64);
  __shared__ float red[8];
  int wave = t >> 6, lane = t & 63;
  if (lane == 0) red[wave] = s;
  __syncthreads();
  float mu = (red[0] + red[1] + red[2] + red[3]) * (1.f/256.f);
  float dx = x - mu;
  float q = dx * dx;
#pragma unroll
  for (int o = 1; o < 64; o <<= 1) q += __shfl_xor(q, o, 64);
  if (lane == 0) red[4 + wave] = q;
  __syncthreads();
  float var = (red[4] + red[5] + red[6] + red[7]) * (1.f/256.f);
  float y = dx * rsqrtf(var + 1e-5f) * g[t] + b[t];
  eln[row*256 + t] = f2bf(y);
}

// ---------------- QKV + EG projection GEMM, LDS-transpose epilogue ----------------
// grid (800, 7): gy 0..5 = one 256-col weight part (Qin,Kin,Vin,Qout,Kout,Vout),
// gy 6 = E/G 64-col tile.  Tile = 32 m-rows x 256 n-cols, 4 waves (n-quarters).
// gy==5 (Vout) uses column-major m-tiles: m = (bn1+t)*160 + n2 so that the
// transposed panel layout packs k-contiguously.
__global__ __launch_bounds__(256) void qkv_gemm_kernel(
    const short* __restrict__ eln, const short* __restrict__ WcT,
    const float* __restrict__ biasc,
    short* __restrict__ Qin, short* __restrict__ Kin, short* __restrict__ Vin,
    short* __restrict__ Qout, short* __restrict__ Kout, short* __restrict__ Vout,
    float* __restrict__ Ein, float* __restrict__ Gin,
    float* __restrict__ Eout, float* __restrict__ Gout) {
  int gy = blockIdx.y;
  int wave = threadIdx.x >> 6, lane = threadIdx.x & 63;
  int lr = lane & 15, lg = lane >> 4;
  __shared__ short T[32][264];

  if (gy < 6) {
    int nb = gy * 256;
    int m0, mstr;
    if (gy == 5) { int n2 = blockIdx.x / 5; int bn1 = (blockIdx.x % 5) * 32; m0 = bn1*160 + n2; mstr = 160; }
    else         { m0 = blockIdx.x * 32; mstr = 1; }
    const short* a0p = eln + (m0 + lr*mstr) * 256;
    const short* a1p = eln + (m0 + (16 + lr)*mstr) * 256;
    int wn = nb + wave * 64;
    const short* b0p = WcT + (wn + lr) * 256;
    floatx4 acc[2][4] = {};
    for (int kk = 0; kk < 256; kk += 32) {
      int ko = kk + lg*8;
      bhalf8 a0 = *(const bhalf8*)(a0p + ko);
      bhalf8 a1 = *(const bhalf8*)(a1p + ko);
#pragma unroll
      for (int f = 0; f < 4; f++) {
        bhalf8 b = *(const bhalf8*)(b0p + f*16*256 + ko);
        acc[0][f] = __builtin_amdgcn_mfma_f32_16x16x32_bf16(a0, b, acc[0][f], 0, 0, 0);
        acc[1][f] = __builtin_amdgcn_mfma_f32_16x16x32_bf16(a1, b, acc[1][f], 0, 0, 0);
      }
    }
#pragma unroll
    for (int i = 0; i < 2; i++)
#pragma unroll
      for (int f = 0; f < 4; f++)
#pragma unroll
        for (int r = 0; r < 4; r++) {
          int mm = i*16 + lg*4 + r;
          int nn = wave*64 + f*16 + lr;
          T[mm][nn] = f2bf(acc[i][f][r] + biasc[nb + nn]);
        }
    __syncthreads();
    if (gy == 2 || gy == 5) {
      // V parts: one thread per col c=(h,d); pack 32 k-contiguous slots = 64B
      int c = threadIdx.x, h = c & 7, d = c >> 3;
      short vals[32];
#pragma unroll
      for (int m = 0; m < 32; m++) vals[m] = T[m][c];
      short* dst;
      if (gy == 2) { int ai = m0 / 160, bj = m0 % 160;
                     dst = Vin + ((ai*8 + h)*32 + d)*160 + bj; }          // [j=n1][h][d][k=n2]
      else         { int n2 = blockIdx.x / 5; int bn1 = (blockIdx.x % 5) * 32;
                     dst = Vout + ((n2*8 + h)*32 + d)*160 + bn1; }        // [j=n2][h][d][k=n1]
#pragma unroll
      for (int q = 0; q < 4; q++) *(bhalf8*)(dst + q*8) = *(const bhalf8*)(vals + q*8);
    } else {
      // Q/K parts: one thread per (m,h); pack 32 d = 64B line
      int m = threadIdx.x >> 3, h = threadIdx.x & 7;
      int ai = m0 / 160, bj = m0 % 160 + m;   // tile never crosses a 160-row (m0 % 160 <= 128)
      short vals[32];
#pragma unroll
      for (int d = 0; d < 32; d++) vals[d] = T[m][h + d*8];
      short* dst;
      if (gy == 0)      dst = Qin  + ((bj*8 + h)*160 + ai)*32;   // [j=n2][h][i=n1][d]
      else if (gy == 1) dst = Kin  + ((ai*8 + h)*160 + bj)*32;   // [j=n1][h][k=n2][d]
      else if (gy == 3) dst = Qout + ((bj*8 + h)*160 + ai)*32;   // [j=n2][h][i=n1][d]
      else              dst = Kout + ((bj*8 + h)*160 + ai)*32;   // [j=n2][h][k=n1][d]
#pragma unroll
      for (int q = 0; q < 4; q++) *(bhalf8*)(dst + q*8) = *(const bhalf8*)(vals + q*8);
    }
  } else {
    // E/G tile: 32 m x 64 n (n = 1536..1599), wave n-quarters of 16
    int m0 = blockIdx.x * 32;
    int wn = 1536 + wave * 16;
    const short* a0p = eln + (m0 + lr) * 256;
    const short* a1p = eln + (m0 + 16 + lr) * 256;
    const short* b0p = WcT + (wn + lr) * 256;
    floatx4 acc[2] = {};
    for (int kk = 0; kk < 256; kk += 32) {
      int ko = kk + lg*8;
      bhalf8 a0 = *(const bhalf8*)(a0p + ko);
      bhalf8 a1 = *(const bhalf8*)(a1p + ko);
      bhalf8 b  = *(const bhalf8*)(b0p + ko);
      acc[0] = __builtin_amdgcn_mfma_f32_16x16x32_bf16(a0, b, acc[0], 0, 0, 0);
      acc[1] = __builtin_amdgcn_mfma_f32_16x16x32_bf16(a1, b, acc[1], 0, 0, 0);
    }
    int n = wn + lr;
    if (n < 1568) {
      int t = n - 1536;             // 0..31
      float* dst = (t < 8) ? Ein : (t < 16) ? Gin : (t < 24) ? Eout : Gout;
#pragma unroll
      for (int i = 0; i < 2; i++)
#pragma unroll
        for (int r = 0; r < 4; r++) {
          int m = m0 + i*16 + lg*4 + r;
          dst[m*8 + (t & 7)] = acc[i][r] + biasc[n];
        }
    }
  }
}

// ---------------- EMS/GSS precompute: [br*8+h][i][k], k contiguous ----------------
__global__ __launch_bounds__(256) void ems_kernel(
    const float* __restrict__ Ein, const float* __restrict__ Gin,
    const float* __restrict__ Eout, const float* __restrict__ Gout,
    const float* __restrict__ mask,
    float* __restrict__ EMS, float* __restrict__ GSS) {
  int idx = blockIdx.x * 256 + threadIdx.x;   // 16*25600 total
  if (idx >= 16 * 25600) return;
  int hb = idx / 25600;
  int rem = idx - hb * 25600;
  int i = rem / 160, k = rem - i * 160;
  int br = hb >> 3, h = hb & 7;
  int src = br ? ((k*160 + i)*8 + h) : ((i*160 + k)*8 + h);
  float ev = br ? Eout[src] : Ein[src];
  float gv = br ? Gout[src] : Gin[src];
  float mv = mask[src];
  EMS[idx] = ev + mv;
  GSS[idx] = 1.f / (1.f + __expf(-(gv + mv)));
}

// ---------------- fused attention: one block per (j, h, branch) ----------------
__global__ __launch_bounds__(256) void attn_kernel(
    const short* __restrict__ Qin, const short* __restrict__ Kin, const short* __restrict__ Vin,
    const short* __restrict__ Qout, const short* __restrict__ Kout, const short* __restrict__ Vout,
    const float* __restrict__ EMS, const float* __restrict__ GSS,
    short* __restrict__ Va) {
  int j = blockIdx.x, h = blockIdx.y, br = blockIdx.z;
  const short* Qg = (br ? Qout : Qin) + (j*8 + h) * 5120;
  const short* Kg = (br ? Kout : Kin) + (j*8 + h) * 5120;
  const short* Vg = (br ? Vout : Vin) + (j*8 + h) * 5120;
  const float* EMh = EMS + (br*8 + h) * 25600;
  const float* GSh = GSS + (br*8 + h) * 25600;
  __shared__ short Qs[5120], Ks[5120], Vs[5120];
  __shared__ short Ps[4][2560];
  for (int t = threadIdx.x; t < 640; t += 256) {
    ((bhalf8*)Qs)[t] = ((const bhalf8*)Qg)[t];
    ((bhalf8*)Ks)[t] = ((const bhalf8*)Kg)[t];
    ((bhalf8*)Vs)[t] = ((const bhalf8*)Vg)[t];
  }
  __syncthreads();
  int wave = threadIdx.x >> 6, lane = threadIdx.x & 63;
  int lr = lane & 15, lg = lane >> 4;
  const floatx4 zero = {0.f, 0.f, 0.f, 0.f};
  for (int qt = wave; qt < 10; qt += 4) {
    bhalf8 aq = *(const bhalf8*)(Qs + (qt*16 + lr)*32 + lg*8);
    int ib = qt*16 + lg*4;
    floatx4 s[10];
#pragma unroll
    for (int kt = 0; kt < 10; kt++) {
      int k = kt*16 + lr;
      floatx4 c0;
      c0[0] = EMh[(ib + 0)*160 + k];
      c0[1] = EMh[(ib + 1)*160 + k];
      c0[2] = EMh[(ib + 2)*160 + k];
      c0[3] = EMh[(ib + 3)*160 + k];
      bhalf8 bk = *(const bhalf8*)(Ks + (kt*16 + lr)*32 + lg*8);
      s[kt] = __builtin_amdgcn_mfma_f32_16x16x32_bf16(aq, bk, c0, 0, 0, 0);
    }
    float mx[4] = {-1e30f, -1e30f, -1e30f, -1e30f};
#pragma unroll
    for (int kt = 0; kt < 10; kt++)
#pragma unroll
      for (int r = 0; r < 4; r++) mx[r] = fmaxf(mx[r], s[kt][r]);
#pragma unroll
    for (int r = 0; r < 4; r++) {
#pragma unroll
      for (int o = 1; o < 16; o <<= 1) mx[r] = fmaxf(mx[r], __shfl_xor(mx[r], o, 64));
    }
    float sm[4] = {0.f, 0.f, 0.f, 0.f};
#pragma unroll
    for (int kt = 0; kt < 10; kt++)
#pragma unroll
      for (int r = 0; r < 4; r++) {
        float p = __expf(s[kt][r] - mx[r]);
        s[kt][r] = p;
        sm[r] += p;
      }
#pragma unroll
    for (int r = 0; r < 4; r++) {
#pragma unroll
      for (int o = 1; o < 16; o <<= 1) sm[r] += __shfl_xor(sm[r], o, 64);
      sm[r] = 1.f / sm[r];
    }
#pragma unroll
    for (int kt = 0; kt < 10; kt++) {
      int k = kt*16 + lr;
#pragma unroll
      for (int r = 0; r < 4; r++) {
        float gate = GSh[(ib + r)*160 + k];
        float aval = s[kt][r] * sm[r] * gate;
        Ps[wave][(lg*4 + r)*160 + k] = f2bf(aval);
      }
    }
    floatx4 accv[2] = {zero, zero};
#pragma unroll
    for (int kc = 0; kc < 5; kc++) {
      bhalf8 ap = *(const bhalf8*)(&Ps[wave][lr*160 + kc*32 + lg*8]);
#pragma unroll
      for (int dt = 0; dt < 2; dt++) {
        bhalf8 bv = *(const bhalf8*)(Vs + (dt*16 + lr)*160 + kc*32 + lg*8);
        accv[dt] = __builtin_amdgcn_mfma_f32_16x16x32_bf16(ap, bv, accv[dt], 0, 0, 0);
      }
    }
    int hh = br*8 + h;
#pragma unroll
    for (int dt = 0; dt < 2; dt++)
#pragma unroll
      for (int r = 0; r < 4; r++) {
        int i = qt*16 + lg*4 + r;
        Va[(i*160 + j)*512 + hh*32 + dt*16 + lr] = f2bf(accv[dt][r]);  // [(i,j)][hh*32+d]
      }
  }
}

// ---------------- output projection GEMM ----------------
__global__ __launch_bounds__(256) void out_gemm_kernel(
    const short* __restrict__ Va, const short* __restrict__ WoT,
    const float* __restrict__ bo, float* __restrict__ out) {
  int bm = blockIdx.x * 64, bn = blockIdx.y * 64;
  int wave = threadIdx.x >> 6, lane = threadIdx.x & 63;
  int wm = bm + (wave >> 1) * 32, wn = bn + (wave & 1) * 32;
  int lr = lane & 15, lg = lane >> 4;
  floatx4 acc[2][2] = {};
  const short* arow0 = Va + (wm + lr) * 512;
  const short* arow1 = Va + (wm + 16 + lr) * 512;
  const short* brow0 = WoT + (wn + lr) * 512;
  const short* brow1 = WoT + (wn + 16 + lr) * 512;
  for (int kk = 0; kk < 512; kk += 32) {
    int ko = kk + lg * 8;
    bhalf8 a0 = *(const bhalf8*)(arow0 + ko);
    bhalf8 a1 = *(const bhalf8*)(arow1 + ko);
    bhalf8 b0 = *(const bhalf8*)(brow0 + ko);
    bhalf8 b1 = *(const bhalf8*)(brow1 + ko);
    acc[0][0] = __builtin_amdgcn_mfma_f32_16x16x32_bf16(a0, b0, acc[0][0], 0, 0, 0);
    acc[0][1] = __builtin_amdgcn_mfma_f32_16x16x32_bf16(a0, b1, acc[0][1], 0, 0, 0);
    acc[1][0] = __builtin_amdgcn_mfma_f32_16x16x32_bf16(a1, b0, acc[1][0], 0, 0, 0);
    acc[1][1] = __builtin_amdgcn_mfma_f32_16x16x32_bf16(a1, b1, acc[1][1], 0, 0, 0);
  }
#pragma unroll
  for (int i = 0; i < 2; i++)
#pragma unroll
    for (int jf = 0; jf < 2; jf++)
#pragma unroll
      for (int r = 0; r < 4; r++) {
        int m = wm + i*16 + lg*4 + r;
        int n = wn + jf*16 + lr;
        out[m*256 + n] = acc[i][jf][r] + bo[n];
      }
}

extern "C" void kernel_launch(void* const* d_in, const int* in_sizes, int n_in,
                              void* d_out, int out_size, void* d_ws, size_t ws_size,
                              hipStream_t stream) {
  const float* e        = (const float*)d_in[0];
  const float* mask     = (const float*)d_in[1];
  const float* ln_g     = (const float*)d_in[2];
  const float* ln_b     = (const float*)d_in[3];
  const float* Wqkv_in  = (const float*)d_in[4];
  const float* bqkv_in  = (const float*)d_in[5];
  const float* Weg_in   = (const float*)d_in[6];
  const float* beg_in   = (const float*)d_in[7];
  const float* Wqkv_out = (const float*)d_in[8];
  const float* bqkv_out = (const float*)d_in[9];
  const float* Weg_out  = (const float*)d_in[10];
  const float* beg_out  = (const float*)d_in[11];
  const float* Wo       = (const float*)d_in[12];
  const float* bo       = (const float*)d_in[13];
  float* out = (float*)d_out;

  char* ws = (char*)d_ws;
  size_t off = 0;
  auto alloc = [&](size_t bytes) -> void* {
    void* p = ws + off;
    off += (bytes + 255) & ~(size_t)255;
    return p;
  };
  short* eln   = (short*)alloc((size_t)MROWS*256*2);
  short* WcT   = (short*)alloc((size_t)NC1*256*2);
  float* biasc = (float*)alloc((size_t)NC1*4);
  short* WoT   = (short*)alloc((size_t)256*512*2);
  short* Qin   = (short*)alloc((size_t)160*8*160*32*2);
  short* Kin   = (short*)alloc((size_t)160*8*160*32*2);
  short* Vin   = (short*)alloc((size_t)160*8*160*32*2);
  short* Qout  = (short*)alloc((size_t)160*8*160*32*2);
  short* Kout  = (short*)alloc((size_t)160*8*160*32*2);
  short* Vout  = (short*)alloc((size_t)160*8*160*32*2);
  float* Ein   = (float*)alloc((size_t)160*160*8*4);
  float* Gin   = (float*)alloc((size_t)160*160*8*4);
  float* Eout  = (float*)alloc((size_t)160*160*8*4);
  float* Gout  = (float*)alloc((size_t)160*160*8*4);
  float* EMS   = (float*)alloc((size_t)16*25600*4);
  float* GSS   = (float*)alloc((size_t)16*25600*4);
  short* Vabuf = (short*)alloc((size_t)MROWS*512*2);

  prep_kernel<<<2112, 256, 0, stream>>>(Wqkv_in, bqkv_in, Weg_in, beg_in,
                                        Wqkv_out, bqkv_out, Weg_out, beg_out,
                                        Wo, WcT, biasc, WoT);
  ln_kernel<<<MROWS, 256, 0, stream>>>(e, ln_g, ln_b, eln);
  qkv_gemm_kernel<<<dim3(800, 7), 256, 0, stream>>>(eln, WcT, biasc,
      Qin, Kin, Vin, Qout, Kout, Vout, Ein, Gin, Eout, Gout);
  ems_kernel<<<1600, 256, 0, stream>>>(Ein, Gin, Eout, Gout, mask, EMS, GSS);
  attn_kernel<<<dim3(160, 8, 2), 256, 0, stream>>>(Qin, Kin, Vin, Qout, Kout, Vout,
      EMS, GSS, Vabuf);
  out_gemm_kernel<<<dim3(400, 4), 256, 0, stream>>>(Vabuf, WoT, bo, out);
}

// Round 5
// 405.209 us; speedup vs baseline: 3.3451x; 1.1061x over previous
//
#include <hip/hip_runtime.h>

#define NDIM 160
#define MROWS (NDIM*NDIM)          // 25600
#define NC1 1600                   // padded projection output cols
#define QK_SCALE 0.17677669529663687f
#define PSW 164                    // Ps row stride: 4-row stride = 328 dw ≡ 8 (mod 32) -> conflict-free

typedef __attribute__((ext_vector_type(8))) short bhalf8;
typedef __attribute__((ext_vector_type(4))) float floatx4;

static __device__ __forceinline__ short f2bf(float f) {
  unsigned int u = __builtin_bit_cast(unsigned int, f);
  u = (u + 0x7FFFu + ((u >> 16) & 1u)) >> 16;
  return (short)(u & 0xFFFFu);
}
static __device__ __forceinline__ float bf2f(unsigned short u) {
  return __builtin_bit_cast(float, ((unsigned int)u) << 16);
}

// ---------------- prep: pack transposed bf16 weights ----------------
__global__ __launch_bounds__(256) void prep_kernel(
    const float* __restrict__ Wqkv_in, const float* __restrict__ bqkv_in,
    const float* __restrict__ Weg_in, const float* __restrict__ beg_in,
    const float* __restrict__ Wqkv_out, const float* __restrict__ bqkv_out,
    const float* __restrict__ Weg_out, const float* __restrict__ beg_out,
    const float* __restrict__ Wo,
    short* __restrict__ WcT, float* __restrict__ biasc, short* __restrict__ WoT) {
  int idx = blockIdx.x * 256 + threadIdx.x;
  if (idx < NC1 * 256) {
    int n = idx >> 8, k = idx & 255;
    float w = 0.f;
    if (n < 768)        { w = Wqkv_in[k*768 + n];          if (n < 256) w *= QK_SCALE; }
    else if (n < 1536)  { int cc = n - 768; w = Wqkv_out[k*768 + cc]; if (cc < 256) w *= QK_SCALE; }
    else if (n < 1552)  { w = Weg_in[k*16 + (n - 1536)]; }
    else if (n < 1568)  { w = Weg_out[k*16 + (n - 1552)]; }
    WcT[n*256 + k] = f2bf(w);
    if (k == 0) {
      float bb = 0.f;
      if (n < 768)        { bb = bqkv_in[n];           if (n < 256) bb *= QK_SCALE; }
      else if (n < 1536)  { int cc = n - 768; bb = bqkv_out[cc]; if (cc < 256) bb *= QK_SCALE; }
      else if (n < 1552)  bb = beg_in[n - 1536];
      else if (n < 1568)  bb = beg_out[n - 1552];
      biasc[n] = bb;
    }
  } else {
    int i2 = idx - NC1 * 256;       // 0 .. 131071  -> WoT[256][512]
    int c = i2 >> 9, cc = i2 & 511;
    // Va slot cc = hh*32 + d ; original channel ch = d*16 + hh
    int ch = (cc & 31) * 16 + (cc >> 5);
    WoT[c*512 + cc] = f2bf(Wo[ch*256 + c]);
  }
}

// ---------------- layernorm -> bf16 ----------------
__global__ __launch_bounds__(256) void ln_kernel(
    const float* __restrict__ e, const float* __restrict__ g,
    const float* __restrict__ b, short* __restrict__ eln) {
  int row = blockIdx.x;
  int t = threadIdx.x;
  float x = e[row*256 + t];
  float s = x;
#pragma unroll
  for (int o = 1; o < 64; o <<= 1) s += __shfl_xor(s, o, 64);
  __shared__ float red[8];
  int wave = t >> 6, lane = t & 63;
  if (lane == 0) red[wave] = s;
  __syncthreads();
  float mu = (red[0] + red[1] + red[2] + red[3]) * (1.f/256.f);
  float dx = x - mu;
  float q = dx * dx;
#pragma unroll
  for (int o = 1; o < 64; o <<= 1) q += __shfl_xor(q, o, 64);
  if (lane == 0) red[4 + wave] = q;
  __syncthreads();
  float var = (red[4] + red[5] + red[6] + red[7]) * (1.f/256.f);
  float y = dx * rsqrtf(var + 1e-5f) * g[t] + b[t];
  eln[row*256 + t] = f2bf(y);
}

// ---------------- QKV + EG projection GEMM, LDS-transpose epilogue ----------------
// grid (800, 7):
//  gy 0..4 (Qin,Kin,Vin,Qout,Kout): 64-row tiles, active x<400 (halves B re-reads)
//  gy 5 (Vout): 32-row col-major tiles, x<800
//  gy 6: E/G 64-col tile, x<800
__global__ __launch_bounds__(256) void qkv_gemm_kernel(
    const short* __restrict__ eln, const short* __restrict__ WcT,
    const float* __restrict__ biasc,
    short* __restrict__ Qin, short* __restrict__ Kin, short* __restrict__ Vin,
    short* __restrict__ Qout, short* __restrict__ Kout, short* __restrict__ Vout,
    float* __restrict__ Ein, float* __restrict__ Gin,
    float* __restrict__ Eout, float* __restrict__ Gout) {
  int gy = blockIdx.y;
  int wave = threadIdx.x >> 6, lane = threadIdx.x & 63;
  int lr = lane & 15, lg = lane >> 4;
  __shared__ short T[32][264];

  if (gy < 5) {
    if (blockIdx.x >= 400) return;
    int nb = gy * 256;
    int m0 = blockIdx.x * 64;
    const short* a0p = eln + (m0 + lr) * 256;
    int wn = nb + wave * 64;
    const short* b0p = WcT + (wn + lr) * 256;
    floatx4 acc[4][4] = {};
    for (int kk = 0; kk < 256; kk += 32) {
      int ko = kk + lg*8;
      bhalf8 a0 = *(const bhalf8*)(a0p + ko);
      bhalf8 a1 = *(const bhalf8*)(a0p + 16*256 + ko);
      bhalf8 a2 = *(const bhalf8*)(a0p + 32*256 + ko);
      bhalf8 a3 = *(const bhalf8*)(a0p + 48*256 + ko);
#pragma unroll
      for (int f = 0; f < 4; f++) {
        bhalf8 b = *(const bhalf8*)(b0p + f*16*256 + ko);
        acc[0][f] = __builtin_amdgcn_mfma_f32_16x16x32_bf16(a0, b, acc[0][f], 0, 0, 0);
        acc[1][f] = __builtin_amdgcn_mfma_f32_16x16x32_bf16(a1, b, acc[1][f], 0, 0, 0);
        acc[2][f] = __builtin_amdgcn_mfma_f32_16x16x32_bf16(a2, b, acc[2][f], 0, 0, 0);
        acc[3][f] = __builtin_amdgcn_mfma_f32_16x16x32_bf16(a3, b, acc[3][f], 0, 0, 0);
      }
    }
#pragma unroll
    for (int half = 0; half < 2; half++) {
      if (half) __syncthreads();
#pragma unroll
      for (int i = 0; i < 2; i++)
#pragma unroll
        for (int f = 0; f < 4; f++)
#pragma unroll
          for (int r = 0; r < 4; r++) {
            int mm = i*16 + lg*4 + r;
            int nn = wave*64 + f*16 + lr;
            T[mm][nn] = f2bf(acc[half*2 + i][f][r] + biasc[nb + nn]);
          }
      __syncthreads();
      int m0h = m0 + half*32;
      int ai = m0h / 160, bj0 = m0h % 160;   // 32-row subtile never crosses a 160-row
      if (gy == 2) {
        // Vin: one thread per col c=(h,d); pack 32 k-contiguous slots = 64B
        int c = threadIdx.x, h = c & 7, d = c >> 3;
        short vals[32];
#pragma unroll
        for (int m = 0; m < 32; m++) vals[m] = T[m][c];
        short* dst = Vin + ((ai*8 + h)*32 + d)*160 + bj0;    // [j=n1][h][d][k=n2]
#pragma unroll
        for (int q = 0; q < 4; q++) *(bhalf8*)(dst + q*8) = *(const bhalf8*)(vals + q*8);
      } else {
        // Q/K: one thread per (m,h); pack 32 d = 64B line
        int m = threadIdx.x >> 3, h = threadIdx.x & 7;
        int bj = bj0 + m;
        short vals[32];
#pragma unroll
        for (int d = 0; d < 32; d++) vals[d] = T[m][h + d*8];
        short* dst;
        if (gy == 0)      dst = Qin  + ((bj*8 + h)*160 + ai)*32;   // [j=n2][h][i=n1][d]
        else if (gy == 1) dst = Kin  + ((ai*8 + h)*160 + bj)*32;   // [j=n1][h][k=n2][d]
        else if (gy == 3) dst = Qout + ((bj*8 + h)*160 + ai)*32;   // [j=n2][h][i=n1][d]
        else              dst = Kout + ((bj*8 + h)*160 + ai)*32;   // [j=n2][h][k=n1][d]
#pragma unroll
        for (int q = 0; q < 4; q++) *(bhalf8*)(dst + q*8) = *(const bhalf8*)(vals + q*8);
      }
    }
  } else if (gy == 5) {
    // Vout: col-major m-tiles: m = (bn1+t)*160 + n2
    int n2 = blockIdx.x / 5; int bn1 = (blockIdx.x % 5) * 32;
    int m0 = bn1*160 + n2;
    const short* a0p = eln + (m0 + lr*160) * 256;
    const short* a1p = eln + (m0 + (16 + lr)*160) * 256;
    int nb = 5 * 256;
    int wn = nb + wave * 64;
    const short* b0p = WcT + (wn + lr) * 256;
    floatx4 acc[2][4] = {};
    for (int kk = 0; kk < 256; kk += 32) {
      int ko = kk + lg*8;
      bhalf8 a0 = *(const bhalf8*)(a0p + ko);
      bhalf8 a1 = *(const bhalf8*)(a1p + ko);
#pragma unroll
      for (int f = 0; f < 4; f++) {
        bhalf8 b = *(const bhalf8*)(b0p + f*16*256 + ko);
        acc[0][f] = __builtin_amdgcn_mfma_f32_16x16x32_bf16(a0, b, acc[0][f], 0, 0, 0);
        acc[1][f] = __builtin_amdgcn_mfma_f32_16x16x32_bf16(a1, b, acc[1][f], 0, 0, 0);
      }
    }
#pragma unroll
    for (int i = 0; i < 2; i++)
#pragma unroll
      for (int f = 0; f < 4; f++)
#pragma unroll
        for (int r = 0; r < 4; r++) {
          int mm = i*16 + lg*4 + r;
          int nn = wave*64 + f*16 + lr;
          T[mm][nn] = f2bf(acc[i][f][r] + biasc[nb + nn]);
        }
    __syncthreads();
    int c = threadIdx.x, h = c & 7, d = c >> 3;
    short vals[32];
#pragma unroll
    for (int m = 0; m < 32; m++) vals[m] = T[m][c];
    short* dst = Vout + ((n2*8 + h)*32 + d)*160 + bn1;        // [j=n2][h][d][k=n1]
#pragma unroll
    for (int q = 0; q < 4; q++) *(bhalf8*)(dst + q*8) = *(const bhalf8*)(vals + q*8);
  } else {
    // E/G tile: 32 m x 64 n (n = 1536..1599), wave n-quarters of 16
    int m0 = blockIdx.x * 32;
    int wn = 1536 + wave * 16;
    const short* a0p = eln + (m0 + lr) * 256;
    const short* a1p = eln + (m0 + 16 + lr) * 256;
    const short* b0p = WcT + (wn + lr) * 256;
    floatx4 acc[2] = {};
    for (int kk = 0; kk < 256; kk += 32) {
      int ko = kk + lg*8;
      bhalf8 a0 = *(const bhalf8*)(a0p + ko);
      bhalf8 a1 = *(const bhalf8*)(a1p + ko);
      bhalf8 b  = *(const bhalf8*)(b0p + ko);
      acc[0] = __builtin_amdgcn_mfma_f32_16x16x32_bf16(a0, b, acc[0], 0, 0, 0);
      acc[1] = __builtin_amdgcn_mfma_f32_16x16x32_bf16(a1, b, acc[1], 0, 0, 0);
    }
    int n = wn + lr;
    if (n < 1568) {
      int t = n - 1536;             // 0..31
      float* dst = (t < 8) ? Ein : (t < 16) ? Gin : (t < 24) ? Eout : Gout;
#pragma unroll
      for (int i = 0; i < 2; i++)
#pragma unroll
        for (int r = 0; r < 4; r++) {
          int m = m0 + i*16 + lg*4 + r;
          dst[m*8 + (t & 7)] = acc[i][r] + biasc[n];
        }
    }
  }
}

// ---------------- EMS/GSS precompute (bf16): [br*8+h][i][k], k contiguous ----------------
__global__ __launch_bounds__(256) void ems_kernel(
    const float* __restrict__ Ein, const float* __restrict__ Gin,
    const float* __restrict__ Eout, const float* __restrict__ Gout,
    const float* __restrict__ mask,
    unsigned short* __restrict__ EMS, unsigned short* __restrict__ GSS) {
  int idx = blockIdx.x * 256 + threadIdx.x;   // 16*25600 total
  if (idx >= 16 * 25600) return;
  int hb = idx / 25600;
  int rem = idx - hb * 25600;
  int i = rem / 160, k = rem - i * 160;
  int br = hb >> 3, h = hb & 7;
  int src = br ? ((k*160 + i)*8 + h) : ((i*160 + k)*8 + h);
  float ev = br ? Eout[src] : Ein[src];
  float gv = br ? Gout[src] : Gin[src];
  float mv = mask[src];
  EMS[idx] = (unsigned short)f2bf(ev + mv);
  GSS[idx] = (unsigned short)f2bf(1.f / (1.f + __expf(-(gv + mv))));
}

// ---------------- fused attention: one block per (j, h, branch), 5 waves ----------------
__global__ __launch_bounds__(320) void attn_kernel(
    const short* __restrict__ Qin, const short* __restrict__ Kin, const short* __restrict__ Vin,
    const short* __restrict__ Qout, const short* __restrict__ Kout, const short* __restrict__ Vout,
    const unsigned short* __restrict__ EMS, const unsigned short* __restrict__ GSS,
    short* __restrict__ Va) {
  int j = blockIdx.x, h = blockIdx.y, br = blockIdx.z;
  const short* Qg = (br ? Qout : Qin) + (j*8 + h) * 5120;
  const short* Kg = (br ? Kout : Kin) + (j*8 + h) * 5120;
  const short* Vg = (br ? Vout : Vin) + (j*8 + h) * 5120;
  const unsigned short* EMh = EMS + (br*8 + h) * 25600;
  const unsigned short* GSh = GSS + (br*8 + h) * 25600;
  __shared__ short Ks[5120], Vs[5120];
  __shared__ short Ps[5][16][PSW];
  // K and V are each 640 bhalf8 chunks -> 1280 total (round-4 bug: bound was 640)
  for (int t = threadIdx.x; t < 1280; t += 320) {
    if (t < 640) ((bhalf8*)Ks)[t] = ((const bhalf8*)Kg)[t];
    else         ((bhalf8*)Vs)[t - 640] = ((const bhalf8*)Vg)[t - 640];
  }
  __syncthreads();
  int wave = threadIdx.x / 64, lane = threadIdx.x & 63;
  int lr = lane & 15, lg = lane >> 4;
  const floatx4 zero = {0.f, 0.f, 0.f, 0.f};
#pragma unroll
  for (int qi = 0; qi < 2; qi++) {
    int qt = wave*2 + qi;
    bhalf8 aq = *(const bhalf8*)(Qg + (qt*16 + lr)*32 + lg*8);
    int ib = qt*16 + lg*4;
    floatx4 s[10];
#pragma unroll
    for (int kt = 0; kt < 10; kt++) {
      int k = kt*16 + lr;
      floatx4 c0;
      c0[0] = bf2f(EMh[(ib + 0)*160 + k]);
      c0[1] = bf2f(EMh[(ib + 1)*160 + k]);
      c0[2] = bf2f(EMh[(ib + 2)*160 + k]);
      c0[3] = bf2f(EMh[(ib + 3)*160 + k]);
      bhalf8 bk = *(const bhalf8*)(Ks + k*32 + lg*8);
      s[kt] = __builtin_amdgcn_mfma_f32_16x16x32_bf16(aq, bk, c0, 0, 0, 0);
    }
    float mx[4] = {-1e30f, -1e30f, -1e30f, -1e30f};
#pragma unroll
    for (int kt = 0; kt < 10; kt++)
#pragma unroll
      for (int r = 0; r < 4; r++) mx[r] = fmaxf(mx[r], s[kt][r]);
#pragma unroll
    for (int r = 0; r < 4; r++) {
#pragma unroll
      for (int o = 1; o < 16; o <<= 1) mx[r] = fmaxf(mx[r], __shfl_xor(mx[r], o, 64));
    }
    float sm[4] = {0.f, 0.f, 0.f, 0.f};
#pragma unroll
    for (int kt = 0; kt < 10; kt++)
#pragma unroll
      for (int r = 0; r < 4; r++) {
        float p = __expf(s[kt][r] - mx[r]);
        s[kt][r] = p;
        sm[r] += p;
      }
#pragma unroll
    for (int r = 0; r < 4; r++) {
#pragma unroll
      for (int o = 1; o < 16; o <<= 1) sm[r] += __shfl_xor(sm[r], o, 64);
      sm[r] = 1.f / sm[r];
    }
#pragma unroll
    for (int kt = 0; kt < 10; kt++) {
      int k = kt*16 + lr;
#pragma unroll
      for (int r = 0; r < 4; r++) {
        float gate = bf2f(GSh[(ib + r)*160 + k]);
        float aval = s[kt][r] * sm[r] * gate;
        Ps[wave][lg*4 + r][k] = f2bf(aval);
      }
    }
    floatx4 accv[2] = {zero, zero};
#pragma unroll
    for (int kc = 0; kc < 5; kc++) {
      bhalf8 ap = *(const bhalf8*)(&Ps[wave][lr][kc*32 + lg*8]);
#pragma unroll
      for (int dt = 0; dt < 2; dt++) {
        bhalf8 bv = *(const bhalf8*)(Vs + (dt*16 + lr)*160 + kc*32 + lg*8);
        accv[dt] = __builtin_amdgcn_mfma_f32_16x16x32_bf16(ap, bv, accv[dt], 0, 0, 0);
      }
    }
    int hh = br*8 + h;
#pragma unroll
    for (int dt = 0; dt < 2; dt++)
#pragma unroll
      for (int r = 0; r < 4; r++) {
        int i = qt*16 + lg*4 + r;
        Va[(i*160 + j)*512 + hh*32 + dt*16 + lr] = f2bf(accv[dt][r]);  // [(i,j)][hh*32+d]
      }
  }
}

// ---------------- output projection GEMM ----------------
__global__ __launch_bounds__(256) void out_gemm_kernel(
    const short* __restrict__ Va, const short* __restrict__ WoT,
    const float* __restrict__ bo, float* __restrict__ out) {
  int bm = blockIdx.x * 64, bn = blockIdx.y * 64;
  int wave = threadIdx.x >> 6, lane = threadIdx.x & 63;
  int wm = bm + (wave >> 1) * 32, wn = bn + (wave & 1) * 32;
  int lr = lane & 15, lg = lane >> 4;
  floatx4 acc[2][2] = {};
  const short* arow0 = Va + (wm + lr) * 512;
  const short* arow1 = Va + (wm + 16 + lr) * 512;
  const short* brow0 = WoT + (wn + lr) * 512;
  const short* brow1 = WoT + (wn + 16 + lr) * 512;
  for (int kk = 0; kk < 512; kk += 32) {
    int ko = kk + lg * 8;
    bhalf8 a0 = *(const bhalf8*)(arow0 + ko);
    bhalf8 a1 = *(const bhalf8*)(arow1 + ko);
    bhalf8 b0 = *(const bhalf8*)(brow0 + ko);
    bhalf8 b1 = *(const bhalf8*)(brow1 + ko);
    acc[0][0] = __builtin_amdgcn_mfma_f32_16x16x32_bf16(a0, b0, acc[0][0], 0, 0, 0);
    acc[0][1] = __builtin_amdgcn_mfma_f32_16x16x32_bf16(a0, b1, acc[0][1], 0, 0, 0);
    acc[1][0] = __builtin_amdgcn_mfma_f32_16x16x32_bf16(a1, b0, acc[1][0], 0, 0, 0);
    acc[1][1] = __builtin_amdgcn_mfma_f32_16x16x32_bf16(a1, b1, acc[1][1], 0, 0, 0);
  }
#pragma unroll
  for (int i = 0; i < 2; i++)
#pragma unroll
    for (int jf = 0; jf < 2; jf++)
#pragma unroll
      for (int r = 0; r < 4; r++) {
        int m = wm + i*16 + lg*4 + r;
        int n = wn + jf*16 + lr;
        out[m*256 + n] = acc[i][jf][r] + bo[n];
      }
}

extern "C" void kernel_launch(void* const* d_in, const int* in_sizes, int n_in,
                              void* d_out, int out_size, void* d_ws, size_t ws_size,
                              hipStream_t stream) {
  const float* e        = (const float*)d_in[0];
  const float* mask     = (const float*)d_in[1];
  const float* ln_g     = (const float*)d_in[2];
  const float* ln_b     = (const float*)d_in[3];
  const float* Wqkv_in  = (const float*)d_in[4];
  const float* bqkv_in  = (const float*)d_in[5];
  const float* Weg_in   = (const float*)d_in[6];
  const float* beg_in   = (const float*)d_in[7];
  const float* Wqkv_out = (const float*)d_in[8];
  const float* bqkv_out = (const float*)d_in[9];
  const float* Weg_out  = (const float*)d_in[10];
  const float* beg_out  = (const float*)d_in[11];
  const float* Wo       = (const float*)d_in[12];
  const float* bo       = (const float*)d_in[13];
  float* out = (float*)d_out;

  char* ws = (char*)d_ws;
  size_t off = 0;
  auto alloc = [&](size_t bytes) -> void* {
    void* p = ws + off;
    off += (bytes + 255) & ~(size_t)255;
    return p;
  };
  short* eln   = (short*)alloc((size_t)MROWS*256*2);
  short* WcT   = (short*)alloc((size_t)NC1*256*2);
  float* biasc = (float*)alloc((size_t)NC1*4);
  short* WoT   = (short*)alloc((size_t)256*512*2);
  short* Qin   = (short*)alloc((size_t)160*8*160*32*2);
  short* Kin   = (short*)alloc((size_t)160*8*160*32*2);
  short* Vin   = (short*)alloc((size_t)160*8*160*32*2);
  short* Qout  = (short*)alloc((size_t)160*8*160*32*2);
  short* Kout  = (short*)alloc((size_t)160*8*160*32*2);
  short* Vout  = (short*)alloc((size_t)160*8*160*32*2);
  float* Ein   = (float*)alloc((size_t)160*160*8*4);
  float* Gin   = (float*)alloc((size_t)160*160*8*4);
  float* Eout  = (float*)alloc((size_t)160*160*8*4);
  float* Gout  = (float*)alloc((size_t)160*160*8*4);
  unsigned short* EMS = (unsigned short*)alloc((size_t)16*25600*2);
  unsigned short* GSS = (unsigned short*)alloc((size_t)16*25600*2);
  short* Vabuf = (short*)alloc((size_t)MROWS*512*2);

  prep_kernel<<<2112, 256, 0, stream>>>(Wqkv_in, bqkv_in, Weg_in, beg_in,
                                        Wqkv_out, bqkv_out, Weg_out, beg_out,
                                        Wo, WcT, biasc, WoT);
  ln_kernel<<<MROWS, 256, 0, stream>>>(e, ln_g, ln_b, eln);
  qkv_gemm_kernel<<<dim3(800, 7), 256, 0, stream>>>(eln, WcT, biasc,
      Qin, Kin, Vin, Qout, Kout, Vout, Ein, Gin, Eout, Gout);
  ems_kernel<<<1600, 256, 0, stream>>>(Ein, Gin, Eout, Gout, mask, EMS, GSS);
  attn_kernel<<<dim3(160, 8, 2), 320, 0, stream>>>(Qin, Kin, Vin, Qout, Kout, Vout,
      EMS, GSS, Vabuf);
  out_gemm_kernel<<<dim3(400, 4), 256, 0, stream>>>(Vabuf, WoT, bo, out);
}

// Round 6
// 348.554 us; speedup vs baseline: 3.8889x; 1.1625x over previous
//
#include <hip/hip_runtime.h>

#define NDIM 160
#define MROWS (NDIM*NDIM)          // 25600
#define NC1 1600                   // padded projection output cols
#define QK_SCALE 0.17677669529663687f
#define PSW 168                    // Ps row stride (shorts): 336B = 16B-aligned; bank stride 84dw≡20 (mod 32) -> ~2-way

typedef __attribute__((ext_vector_type(8))) short bhalf8;
typedef __attribute__((ext_vector_type(4))) short short4v;
typedef __attribute__((ext_vector_type(4))) unsigned short ushort4v;
typedef __attribute__((ext_vector_type(4))) float floatx4;

static __device__ __forceinline__ short f2bf(float f) {
  unsigned int u = __builtin_bit_cast(unsigned int, f);
  u = (u + 0x7FFFu + ((u >> 16) & 1u)) >> 16;
  return (short)(u & 0xFFFFu);
}
static __device__ __forceinline__ float bf2f(unsigned short u) {
  return __builtin_bit_cast(float, ((unsigned int)u) << 16);
}

// ---------------- prep: pack transposed bf16 weights ----------------
__global__ __launch_bounds__(256) void prep_kernel(
    const float* __restrict__ Wqkv_in, const float* __restrict__ bqkv_in,
    const float* __restrict__ Weg_in, const float* __restrict__ beg_in,
    const float* __restrict__ Wqkv_out, const float* __restrict__ bqkv_out,
    const float* __restrict__ Weg_out, const float* __restrict__ beg_out,
    const float* __restrict__ Wo,
    short* __restrict__ WcT, float* __restrict__ biasc, short* __restrict__ WoT) {
  int idx = blockIdx.x * 256 + threadIdx.x;
  if (idx < NC1 * 256) {
    int n = idx >> 8, k = idx & 255;
    float w = 0.f;
    if (n < 768)        { w = Wqkv_in[k*768 + n];          if (n < 256) w *= QK_SCALE; }
    else if (n < 1536)  { int cc = n - 768; w = Wqkv_out[k*768 + cc]; if (cc < 256) w *= QK_SCALE; }
    else if (n < 1552)  { w = Weg_in[k*16 + (n - 1536)]; }
    else if (n < 1568)  { w = Weg_out[k*16 + (n - 1552)]; }
    WcT[n*256 + k] = f2bf(w);
    if (k == 0) {
      float bb = 0.f;
      if (n < 768)        { bb = bqkv_in[n];           if (n < 256) bb *= QK_SCALE; }
      else if (n < 1536)  { int cc = n - 768; bb = bqkv_out[cc]; if (cc < 256) bb *= QK_SCALE; }
      else if (n < 1552)  bb = beg_in[n - 1536];
      else if (n < 1568)  bb = beg_out[n - 1552];
      biasc[n] = bb;
    }
  } else {
    int i2 = idx - NC1 * 256;       // 0 .. 131071  -> WoT[256][512]
    int c = i2 >> 9, cc = i2 & 511;
    // Va slot cc = hh*32 + d ; original channel ch = d*16 + hh
    int ch = (cc & 31) * 16 + (cc >> 5);
    WoT[c*512 + cc] = f2bf(Wo[ch*256 + c]);
  }
}

// ---------------- layernorm -> bf16 ----------------
__global__ __launch_bounds__(256) void ln_kernel(
    const float* __restrict__ e, const float* __restrict__ g,
    const float* __restrict__ b, short* __restrict__ eln) {
  int row = blockIdx.x;
  int t = threadIdx.x;
  float x = e[row*256 + t];
  float s = x;
#pragma unroll
  for (int o = 1; o < 64; o <<= 1) s += __shfl_xor(s, o, 64);
  __shared__ float red[8];
  int wave = t >> 6, lane = t & 63;
  if (lane == 0) red[wave] = s;
  __syncthreads();
  float mu = (red[0] + red[1] + red[2] + red[3]) * (1.f/256.f);
  float dx = x - mu;
  float q = dx * dx;
#pragma unroll
  for (int o = 1; o < 64; o <<= 1) q += __shfl_xor(q, o, 64);
  if (lane == 0) red[4 + wave] = q;
  __syncthreads();
  float var = (red[4] + red[5] + red[6] + red[7]) * (1.f/256.f);
  float y = dx * rsqrtf(var + 1e-5f) * g[t] + b[t];
  eln[row*256 + t] = f2bf(y);
}

// ---------------- QKV + EG projection GEMM, LDS-transpose epilogue ----------------
// grid (800, 7):
//  gy 0..4 (Qin,Kin,Vin,Qout,Kout): 64-row tiles, active x<400
//  gy 5 (Vout): 32-row col-major tiles, x<800
//  gy 6: E/G 64-col tile, x<800
__global__ __launch_bounds__(256) void qkv_gemm_kernel(
    const short* __restrict__ eln, const short* __restrict__ WcT,
    const float* __restrict__ biasc,
    short* __restrict__ Qin, short* __restrict__ Kin, short* __restrict__ Vin,
    short* __restrict__ Qout, short* __restrict__ Kout, short* __restrict__ Vout,
    float* __restrict__ Ein, float* __restrict__ Gin,
    float* __restrict__ Eout, float* __restrict__ Gout) {
  int gy = blockIdx.y;
  int wave = threadIdx.x >> 6, lane = threadIdx.x & 63;
  int lr = lane & 15, lg = lane >> 4;
  __shared__ short T[32][264];

  if (gy < 5) {
    if (blockIdx.x >= 400) return;
    int nb = gy * 256;
    int m0 = blockIdx.x * 64;
    const short* a0p = eln + (m0 + lr) * 256;
    int wn = nb + wave * 64;
    const short* b0p = WcT + (wn + lr) * 256;
    floatx4 acc[4][4] = {};
    for (int kk = 0; kk < 256; kk += 32) {
      int ko = kk + lg*8;
      bhalf8 a0 = *(const bhalf8*)(a0p + ko);
      bhalf8 a1 = *(const bhalf8*)(a0p + 16*256 + ko);
      bhalf8 a2 = *(const bhalf8*)(a0p + 32*256 + ko);
      bhalf8 a3 = *(const bhalf8*)(a0p + 48*256 + ko);
#pragma unroll
      for (int f = 0; f < 4; f++) {
        bhalf8 b = *(const bhalf8*)(b0p + f*16*256 + ko);
        acc[0][f] = __builtin_amdgcn_mfma_f32_16x16x32_bf16(a0, b, acc[0][f], 0, 0, 0);
        acc[1][f] = __builtin_amdgcn_mfma_f32_16x16x32_bf16(a1, b, acc[1][f], 0, 0, 0);
        acc[2][f] = __builtin_amdgcn_mfma_f32_16x16x32_bf16(a2, b, acc[2][f], 0, 0, 0);
        acc[3][f] = __builtin_amdgcn_mfma_f32_16x16x32_bf16(a3, b, acc[3][f], 0, 0, 0);
      }
    }
#pragma unroll
    for (int half = 0; half < 2; half++) {
      if (half) __syncthreads();
#pragma unroll
      for (int i = 0; i < 2; i++)
#pragma unroll
        for (int f = 0; f < 4; f++)
#pragma unroll
          for (int r = 0; r < 4; r++) {
            int mm = i*16 + lg*4 + r;
            int nn = wave*64 + f*16 + lr;
            T[mm][nn] = f2bf(acc[half*2 + i][f][r] + biasc[nb + nn]);
          }
      __syncthreads();
      int m0h = m0 + half*32;
      int ai = m0h / 160, bj0 = m0h % 160;
      if (gy == 2) {
        int c = threadIdx.x, h = c & 7, d = c >> 3;
        short vals[32];
#pragma unroll
        for (int m = 0; m < 32; m++) vals[m] = T[m][c];
        short* dst = Vin + ((ai*8 + h)*32 + d)*160 + bj0;    // [j=n1][h][d][k=n2]
#pragma unroll
        for (int q = 0; q < 4; q++) *(bhalf8*)(dst + q*8) = *(const bhalf8*)(vals + q*8);
      } else {
        int m = threadIdx.x >> 3, h = threadIdx.x & 7;
        int bj = bj0 + m;
        short vals[32];
#pragma unroll
        for (int d = 0; d < 32; d++) vals[d] = T[m][h + d*8];
        short* dst;
        if (gy == 0)      dst = Qin  + ((bj*8 + h)*160 + ai)*32;   // [j=n2][h][i=n1][d]
        else if (gy == 1) dst = Kin  + ((ai*8 + h)*160 + bj)*32;   // [j=n1][h][k=n2][d]
        else if (gy == 3) dst = Qout + ((bj*8 + h)*160 + ai)*32;   // [j=n2][h][i=n1][d]
        else              dst = Kout + ((bj*8 + h)*160 + ai)*32;   // [j=n2][h][k=n1][d]
#pragma unroll
        for (int q = 0; q < 4; q++) *(bhalf8*)(dst + q*8) = *(const bhalf8*)(vals + q*8);
      }
    }
  } else if (gy == 5) {
    // Vout: col-major m-tiles: m = (bn1+t)*160 + n2
    int n2 = blockIdx.x / 5; int bn1 = (blockIdx.x % 5) * 32;
    int m0 = bn1*160 + n2;
    const short* a0p = eln + (m0 + lr*160) * 256;
    const short* a1p = eln + (m0 + (16 + lr)*160) * 256;
    int nb = 5 * 256;
    int wn = nb + wave * 64;
    const short* b0p = WcT + (wn + lr) * 256;
    floatx4 acc[2][4] = {};
    for (int kk = 0; kk < 256; kk += 32) {
      int ko = kk + lg*8;
      bhalf8 a0 = *(const bhalf8*)(a0p + ko);
      bhalf8 a1 = *(const bhalf8*)(a1p + ko);
#pragma unroll
      for (int f = 0; f < 4; f++) {
        bhalf8 b = *(const bhalf8*)(b0p + f*16*256 + ko);
        acc[0][f] = __builtin_amdgcn_mfma_f32_16x16x32_bf16(a0, b, acc[0][f], 0, 0, 0);
        acc[1][f] = __builtin_amdgcn_mfma_f32_16x16x32_bf16(a1, b, acc[1][f], 0, 0, 0);
      }
    }
#pragma unroll
    for (int i = 0; i < 2; i++)
#pragma unroll
      for (int f = 0; f < 4; f++)
#pragma unroll
        for (int r = 0; r < 4; r++) {
          int mm = i*16 + lg*4 + r;
          int nn = wave*64 + f*16 + lr;
          T[mm][nn] = f2bf(acc[i][f][r] + biasc[nb + nn]);
        }
    __syncthreads();
    int c = threadIdx.x, h = c & 7, d = c >> 3;
    short vals[32];
#pragma unroll
    for (int m = 0; m < 32; m++) vals[m] = T[m][c];
    short* dst = Vout + ((n2*8 + h)*32 + d)*160 + bn1;        // [j=n2][h][d][k=n1]
#pragma unroll
    for (int q = 0; q < 4; q++) *(bhalf8*)(dst + q*8) = *(const bhalf8*)(vals + q*8);
  } else {
    // E/G tile: 32 m x 64 n (n = 1536..1599)
    int m0 = blockIdx.x * 32;
    int wn = 1536 + wave * 16;
    const short* a0p = eln + (m0 + lr) * 256;
    const short* a1p = eln + (m0 + 16 + lr) * 256;
    const short* b0p = WcT + (wn + lr) * 256;
    floatx4 acc[2] = {};
    for (int kk = 0; kk < 256; kk += 32) {
      int ko = kk + lg*8;
      bhalf8 a0 = *(const bhalf8*)(a0p + ko);
      bhalf8 a1 = *(const bhalf8*)(a1p + ko);
      bhalf8 b  = *(const bhalf8*)(b0p + ko);
      acc[0] = __builtin_amdgcn_mfma_f32_16x16x32_bf16(a0, b, acc[0], 0, 0, 0);
      acc[1] = __builtin_amdgcn_mfma_f32_16x16x32_bf16(a1, b, acc[1], 0, 0, 0);
    }
    int n = wn + lr;
    if (n < 1568) {
      int t = n - 1536;
      float* dst = (t < 8) ? Ein : (t < 16) ? Gin : (t < 24) ? Eout : Gout;
#pragma unroll
      for (int i = 0; i < 2; i++)
#pragma unroll
        for (int r = 0; r < 4; r++) {
          int m = m0 + i*16 + lg*4 + r;
          dst[m*8 + (t & 7)] = acc[i][r] + biasc[n];
        }
    }
  }
}

// ---------------- EMS/GSS precompute (bf16): [br*8+h][i][k], k contiguous ----------------
__global__ __launch_bounds__(256) void ems_kernel(
    const float* __restrict__ Ein, const float* __restrict__ Gin,
    const float* __restrict__ Eout, const float* __restrict__ Gout,
    const float* __restrict__ mask,
    unsigned short* __restrict__ EMS, unsigned short* __restrict__ GSS) {
  int idx = blockIdx.x * 256 + threadIdx.x;   // 16*25600 total
  if (idx >= 16 * 25600) return;
  int hb = idx / 25600;
  int rem = idx - hb * 25600;
  int i = rem / 160, k = rem - i * 160;
  int br = hb >> 3, h = hb & 7;
  int src = br ? ((k*160 + i)*8 + h) : ((i*160 + k)*8 + h);
  float ev = br ? Eout[src] : Ein[src];
  float gv = br ? Gout[src] : Gin[src];
  float mv = mask[src];
  EMS[idx] = (unsigned short)f2bf(ev + mv);
  GSS[idx] = (unsigned short)f2bf(1.f / (1.f + __expf(-(gv + mv))));
}

// ---------------- fused attention v2: wave-independent, S^T via mfma(K,Q) ----------------
// one wave per (j, h, br, qt-pair); 4 waves/block; no barriers; no K/V staging.
// Lane (lr,lg) after QK holds S[k=kt*16+lg*4+r][i=qt*16+lr] -> softmax over k is
// lane-local + 2 shfl; EMS/GSS reads are contiguous 8B; P^T -> Ps via b64 writes.
__global__ __launch_bounds__(256) void attn_kernel(
    const short* __restrict__ Qin, const short* __restrict__ Kin, const short* __restrict__ Vin,
    const short* __restrict__ Qout, const short* __restrict__ Kout, const short* __restrict__ Vout,
    const unsigned short* __restrict__ EMS, const unsigned short* __restrict__ GSS,
    short* __restrict__ Va) {
  int wave = threadIdx.x >> 6, lane = threadIdx.x & 63;
  int g = blockIdx.x * 4 + wave;          // 0..12799
  int pair = g % 5;
  int u = g / 5;                          // 0..2559
  int h = u & 7;
  int v = u >> 3;                         // 0..319
  int br = v & 1;
  int j = v >> 1;                         // 0..159
  int lr = lane & 15, lg = lane >> 4;
  const short* Qg = (br ? Qout : Qin) + (j*8 + h) * 5120;   // [i][d]
  const short* Kg = (br ? Kout : Kin) + (j*8 + h) * 5120;   // [k][d]
  const short* Vg = (br ? Vout : Vin) + (j*8 + h) * 5120;   // [d][k]
  const unsigned short* EMh = EMS + (br*8 + h) * 25600;     // [i][k]
  const unsigned short* GSh = GSS + (br*8 + h) * 25600;
  __shared__ short Ps[4][16][PSW];

  // K A-fragments, reused for both qt of the pair
  bhalf8 kf[10];
#pragma unroll
  for (int kt = 0; kt < 10; kt++)
    kf[kt] = *(const bhalf8*)(Kg + (kt*16 + lr)*32 + lg*8);

  const floatx4 zero = {0.f, 0.f, 0.f, 0.f};
  int hh = br*8 + h;
#pragma unroll
  for (int qi = 0; qi < 2; qi++) {
    int qt = pair*2 + qi;
    int i0 = qt*16;
    bhalf8 qf = *(const bhalf8*)(Qg + (i0 + lr)*32 + lg*8);
    int erow = (i0 + lr)*160;
    floatx4 s[10];
#pragma unroll
    for (int kt = 0; kt < 10; kt++) {
      ushort4v em = *(const ushort4v*)(EMh + erow + kt*16 + lg*4);
      floatx4 c0;
      c0[0] = bf2f(em[0]); c0[1] = bf2f(em[1]); c0[2] = bf2f(em[2]); c0[3] = bf2f(em[3]);
      s[kt] = __builtin_amdgcn_mfma_f32_16x16x32_bf16(kf[kt], qf, c0, 0, 0, 0); // D[k][i]
    }
    float mx = -1e30f;
#pragma unroll
    for (int kt = 0; kt < 10; kt++)
#pragma unroll
      for (int r = 0; r < 4; r++) mx = fmaxf(mx, s[kt][r]);
    mx = fmaxf(mx, __shfl_xor(mx, 16, 64));
    mx = fmaxf(mx, __shfl_xor(mx, 32, 64));
    float sm = 0.f;
#pragma unroll
    for (int kt = 0; kt < 10; kt++)
#pragma unroll
      for (int r = 0; r < 4; r++) {
        float p = __expf(s[kt][r] - mx);
        s[kt][r] = p;
        sm += p;
      }
    sm += __shfl_xor(sm, 16, 64);
    sm += __shfl_xor(sm, 32, 64);
    float rs = 1.f / sm;
    // gate + write P^T -> Ps[i_local=lr][k], 4 contiguous bf16 per kt
#pragma unroll
    for (int kt = 0; kt < 10; kt++) {
      ushort4v gs = *(const ushort4v*)(GSh + erow + kt*16 + lg*4);
      short4v pk;
      pk[0] = f2bf(s[kt][0] * rs * bf2f(gs[0]));
      pk[1] = f2bf(s[kt][1] * rs * bf2f(gs[1]));
      pk[2] = f2bf(s[kt][2] * rs * bf2f(gs[2]));
      pk[3] = f2bf(s[kt][3] * rs * bf2f(gs[3]));
      *(short4v*)(&Ps[wave][lr][kt*16 + lg*4]) = pk;
    }
    // PV: A = P rows (from Ps), B = V^T rows (global, [d][k])
    floatx4 accv0 = zero, accv1 = zero;
#pragma unroll
    for (int kc = 0; kc < 5; kc++) {
      bhalf8 ap  = *(const bhalf8*)(&Ps[wave][lr][kc*32 + lg*8]);
      bhalf8 bv0 = *(const bhalf8*)(Vg + lr*160 + kc*32 + lg*8);
      bhalf8 bv1 = *(const bhalf8*)(Vg + (16 + lr)*160 + kc*32 + lg*8);
      accv0 = __builtin_amdgcn_mfma_f32_16x16x32_bf16(ap, bv0, accv0, 0, 0, 0);
      accv1 = __builtin_amdgcn_mfma_f32_16x16x32_bf16(ap, bv1, accv1, 0, 0, 0);
    }
#pragma unroll
    for (int r = 0; r < 4; r++) {
      int i = i0 + lg*4 + r;
      short* vp = Va + (i*160 + j)*512 + hh*32;
      vp[lr]      = f2bf(accv0[r]);
      vp[16 + lr] = f2bf(accv1[r]);
    }
  }
}

// ---------------- output projection GEMM ----------------
__global__ __launch_bounds__(256) void out_gemm_kernel(
    const short* __restrict__ Va, const short* __restrict__ WoT,
    const float* __restrict__ bo, float* __restrict__ out) {
  int bm = blockIdx.x * 64, bn = blockIdx.y * 64;
  int wave = threadIdx.x >> 6, lane = threadIdx.x & 63;
  int wm = bm + (wave >> 1) * 32, wn = bn + (wave & 1) * 32;
  int lr = lane & 15, lg = lane >> 4;
  floatx4 acc[2][2] = {};
  const short* arow0 = Va + (wm + lr) * 512;
  const short* arow1 = Va + (wm + 16 + lr) * 512;
  const short* brow0 = WoT + (wn + lr) * 512;
  const short* brow1 = WoT + (wn + 16 + lr) * 512;
  for (int kk = 0; kk < 512; kk += 32) {
    int ko = kk + lg * 8;
    bhalf8 a0 = *(const bhalf8*)(arow0 + ko);
    bhalf8 a1 = *(const bhalf8*)(arow1 + ko);
    bhalf8 b0 = *(const bhalf8*)(brow0 + ko);
    bhalf8 b1 = *(const bhalf8*)(brow1 + ko);
    acc[0][0] = __builtin_amdgcn_mfma_f32_16x16x32_bf16(a0, b0, acc[0][0], 0, 0, 0);
    acc[0][1] = __builtin_amdgcn_mfma_f32_16x16x32_bf16(a0, b1, acc[0][1], 0, 0, 0);
    acc[1][0] = __builtin_amdgcn_mfma_f32_16x16x32_bf16(a1, b0, acc[1][0], 0, 0, 0);
    acc[1][1] = __builtin_amdgcn_mfma_f32_16x16x32_bf16(a1, b1, acc[1][1], 0, 0, 0);
  }
#pragma unroll
  for (int i = 0; i < 2; i++)
#pragma unroll
    for (int jf = 0; jf < 2; jf++)
#pragma unroll
      for (int r = 0; r < 4; r++) {
        int m = wm + i*16 + lg*4 + r;
        int n = wn + jf*16 + lr;
        out[m*256 + n] = acc[i][jf][r] + bo[n];
      }
}

extern "C" void kernel_launch(void* const* d_in, const int* in_sizes, int n_in,
                              void* d_out, int out_size, void* d_ws, size_t ws_size,
                              hipStream_t stream) {
  const float* e        = (const float*)d_in[0];
  const float* mask     = (const float*)d_in[1];
  const float* ln_g     = (const float*)d_in[2];
  const float* ln_b     = (const float*)d_in[3];
  const float* Wqkv_in  = (const float*)d_in[4];
  const float* bqkv_in  = (const float*)d_in[5];
  const float* Weg_in   = (const float*)d_in[6];
  const float* beg_in   = (const float*)d_in[7];
  const float* Wqkv_out = (const float*)d_in[8];
  const float* bqkv_out = (const float*)d_in[9];
  const float* Weg_out  = (const float*)d_in[10];
  const float* beg_out  = (const float*)d_in[11];
  const float* Wo       = (const float*)d_in[12];
  const float* bo       = (const float*)d_in[13];
  float* out = (float*)d_out;

  char* ws = (char*)d_ws;
  size_t off = 0;
  auto alloc = [&](size_t bytes) -> void* {
    void* p = ws + off;
    off += (bytes + 255) & ~(size_t)255;
    return p;
  };
  short* eln   = (short*)alloc((size_t)MROWS*256*2);
  short* WcT   = (short*)alloc((size_t)NC1*256*2);
  float* biasc = (float*)alloc((size_t)NC1*4);
  short* WoT   = (short*)alloc((size_t)256*512*2);
  short* Qin   = (short*)alloc((size_t)160*8*160*32*2);
  short* Kin   = (short*)alloc((size_t)160*8*160*32*2);
  short* Vin   = (short*)alloc((size_t)160*8*160*32*2);
  short* Qout  = (short*)alloc((size_t)160*8*160*32*2);
  short* Kout  = (short*)alloc((size_t)160*8*160*32*2);
  short* Vout  = (short*)alloc((size_t)160*8*160*32*2);
  float* Ein   = (float*)alloc((size_t)160*160*8*4);
  float* Gin   = (float*)alloc((size_t)160*160*8*4);
  float* Eout  = (float*)alloc((size_t)160*160*8*4);
  float* Gout  = (float*)alloc((size_t)160*160*8*4);
  unsigned short* EMS = (unsigned short*)alloc((size_t)16*25600*2);
  unsigned short* GSS = (unsigned short*)alloc((size_t)16*25600*2);
  short* Vabuf = (short*)alloc((size_t)MROWS*512*2);

  prep_kernel<<<2112, 256, 0, stream>>>(Wqkv_in, bqkv_in, Weg_in, beg_in,
                                        Wqkv_out, bqkv_out, Weg_out, beg_out,
                                        Wo, WcT, biasc, WoT);
  ln_kernel<<<MROWS, 256, 0, stream>>>(e, ln_g, ln_b, eln);
  qkv_gemm_kernel<<<dim3(800, 7), 256, 0, stream>>>(eln, WcT, biasc,
      Qin, Kin, Vin, Qout, Kout, Vout, Ein, Gin, Eout, Gout);
  ems_kernel<<<1600, 256, 0, stream>>>(Ein, Gin, Eout, Gout, mask, EMS, GSS);
  attn_kernel<<<3200, 256, 0, stream>>>(Qin, Kin, Vin, Qout, Kout, Vout,
      EMS, GSS, Vabuf);
  out_gemm_kernel<<<dim3(400, 4), 256, 0, stream>>>(Vabuf, WoT, bo, out);
}

// Round 7
// 284.782 us; speedup vs baseline: 4.7597x; 1.2239x over previous
//
#include <hip/hip_runtime.h>

#define NDIM 160
#define MROWS (NDIM*NDIM)          // 25600
#define NC1 1600                   // packed projection output cols
#define QK_SCALE 0.17677669529663687f
#define PSW 168                    // attn Ps row stride (shorts)

typedef __attribute__((ext_vector_type(8))) short bhalf8;
typedef __attribute__((ext_vector_type(4))) short short4v;
typedef __attribute__((ext_vector_type(4))) unsigned short ushort4v;
typedef __attribute__((ext_vector_type(4))) float floatx4;

static __device__ __forceinline__ short f2bf(float f) {
  unsigned int u = __builtin_bit_cast(unsigned int, f);
  u = (u + 0x7FFFu + ((u >> 16) & 1u)) >> 16;
  return (short)(u & 0xFFFFu);
}
static __device__ __forceinline__ float bf2f(unsigned short u) {
  return __builtin_bit_cast(float, ((unsigned int)u) << 16);
}
static __device__ __forceinline__ void gload_lds16(const short* g, short* l) {
  __builtin_amdgcn_global_load_lds(
      (const __attribute__((address_space(1))) void*)g,
      (__attribute__((address_space(3))) void*)l, 16, 0, 0);
}

// ---------------- prep: pack transposed bf16 weights ----------------
__global__ __launch_bounds__(256) void prep_kernel(
    const float* __restrict__ Wqkv_in, const float* __restrict__ bqkv_in,
    const float* __restrict__ Weg_in, const float* __restrict__ beg_in,
    const float* __restrict__ Wqkv_out, const float* __restrict__ bqkv_out,
    const float* __restrict__ Weg_out, const float* __restrict__ beg_out,
    const float* __restrict__ Wo,
    short* __restrict__ WcT, float* __restrict__ biasc, short* __restrict__ WoT) {
  int idx = blockIdx.x * 256 + threadIdx.x;
  if (idx < NC1 * 256) {
    int n = idx >> 8, k = idx & 255;
    float w = 0.f;
    if (n < 768)        { w = Wqkv_in[k*768 + n];          if (n < 256) w *= QK_SCALE; }
    else if (n < 1536)  { int cc = n - 768; w = Wqkv_out[k*768 + cc]; if (cc < 256) w *= QK_SCALE; }
    else if (n < 1552)  { w = Weg_in[k*16 + (n - 1536)]; }
    else if (n < 1568)  { w = Weg_out[k*16 + (n - 1552)]; }
    WcT[n*256 + k] = f2bf(w);
    if (k == 0) {
      float bb = 0.f;
      if (n < 768)        { bb = bqkv_in[n];           if (n < 256) bb *= QK_SCALE; }
      else if (n < 1536)  { int cc = n - 768; bb = bqkv_out[cc]; if (cc < 256) bb *= QK_SCALE; }
      else if (n < 1552)  bb = beg_in[n - 1536];
      else if (n < 1568)  bb = beg_out[n - 1552];
      biasc[n] = bb;
    }
  } else {
    int i2 = idx - NC1 * 256;       // 0 .. 131071  -> WoT[256][512]
    int c = i2 >> 9, cc = i2 & 511;
    int ch = (cc & 31) * 16 + (cc >> 5);    // Va slot cc = hh*32 + d
    WoT[c*512 + cc] = f2bf(Wo[ch*256 + c]);
  }
}

// ---------------- layernorm -> bf16 : 1 wave per row, float4 ----------------
__global__ __launch_bounds__(256) void ln_kernel(
    const float* __restrict__ e, const float* __restrict__ g,
    const float* __restrict__ b, short* __restrict__ eln) {
  int row = blockIdx.x * 4 + (threadIdx.x >> 6);
  int lane = threadIdx.x & 63;
  float4 x = ((const float4*)(e + row*256))[lane];
  float s = x.x + x.y + x.z + x.w;
#pragma unroll
  for (int o = 1; o < 64; o <<= 1) s += __shfl_xor(s, o, 64);
  float mu = s * (1.f/256.f);
  float dx0 = x.x - mu, dx1 = x.y - mu, dx2 = x.z - mu, dx3 = x.w - mu;
  float q = dx0*dx0 + dx1*dx1 + dx2*dx2 + dx3*dx3;
#pragma unroll
  for (int o = 1; o < 64; o <<= 1) q += __shfl_xor(q, o, 64);
  float rstd = rsqrtf(q * (1.f/256.f) + 1e-5f);
  float4 gg = ((const float4*)g)[lane];
  float4 bb = ((const float4*)b)[lane];
  short4v y;
  y[0] = f2bf(dx0 * rstd * gg.x + bb.x);
  y[1] = f2bf(dx1 * rstd * gg.y + bb.y);
  y[2] = f2bf(dx2 * rstd * gg.z + bb.z);
  y[3] = f2bf(dx3 * rstd * gg.w + bb.w);
  ((short4v*)(eln + row*256))[lane] = y;
}

// ---------------- m97-style 128x128 GEMM main loop (BK=32, LDS dbuf) ----------------
// SMEM layout (shorts): A[buf0]=0..4095, A[buf1]=4096..8191, B[buf0]=8192.., B[buf1]=12288..
// wave (wr=wave>>1, wc=wave&1) computes C[wr*64 + mi*16 + lg*4 + r][wc*64 + ni*16 + lr]
template<int K>
static __device__ __forceinline__ void gemm128_mainloop(
    const short* __restrict__ A0, const short* __restrict__ B0,
    short* SMEM, floatx4 (&acc)[4][4]) {
  const int wave = threadIdx.x >> 6, lane = threadIdx.x & 63;
  const int lr = lane & 15, lg = lane >> 4;
  const int wr = wave >> 1, wc = wave & 1;
  const int srow = (lane >> 2);              // 0..15 within 16-row group
  const int scol = (lane & 3) * 8;           // shorts
  constexpr int NSTEP = K / 32;

  auto stage = [&](int bsel, int s) {
#pragma unroll
    for (int q = 0; q < 2; q++) {
      int rbase = wave*32 + q*16;
      const short* ga = A0 + (rbase + srow)*K + s*32 + scol;
      short* la = SMEM + bsel*4096 + rbase*32;             // wave-uniform base
      gload_lds16(ga, la);
      const short* gb = B0 + (rbase + srow)*K + s*32 + scol;
      short* lb = SMEM + 8192 + bsel*4096 + rbase*32;
      gload_lds16(gb, lb);
    }
  };

  stage(0, 0);
  __syncthreads();
  int bsel = 0;
  for (int s = 0; s < NSTEP; s++) {
    if (s + 1 < NSTEP) stage(bsel ^ 1, s + 1);
    bhalf8 af[4], bf[4];
#pragma unroll
    for (int mi = 0; mi < 4; mi++)
      af[mi] = *(const bhalf8*)(SMEM + bsel*4096 + (wr*64 + mi*16 + lr)*32 + lg*8);
#pragma unroll
    for (int ni = 0; ni < 4; ni++)
      bf[ni] = *(const bhalf8*)(SMEM + 8192 + bsel*4096 + (wc*64 + ni*16 + lr)*32 + lg*8);
#pragma unroll
    for (int mi = 0; mi < 4; mi++)
#pragma unroll
      for (int ni = 0; ni < 4; ni++)
        acc[mi][ni] = __builtin_amdgcn_mfma_f32_16x16x32_bf16(af[mi], bf[ni], acc[mi][ni], 0, 0, 0);
    __syncthreads();
    bsel ^= 1;
  }
}

// ---------------- QKV projection (parts 0..4: Qin,Kin,Vin,Qout,Kout) ----------------
// grid (10, 200): x = n-tile (part=x>>1, half=x&1), y = m-tile (128 rows)
__global__ __launch_bounds__(256) void qkv_gemm128_kernel(
    const short* __restrict__ eln, const short* __restrict__ WcT,
    const float* __restrict__ biasc,
    short* __restrict__ Qin, short* __restrict__ Kin, short* __restrict__ Vin,
    short* __restrict__ Qout, short* __restrict__ Kout) {
  int nt = blockIdx.x, mt = blockIdx.y;
  int part = nt >> 1;
  int n0 = part*256 + (nt & 1)*128;
  int m0 = mt * 128;
  __shared__ short SMEM[16384];
  floatx4 acc[4][4] = {};
  gemm128_mainloop<256>(eln + (size_t)m0*256, WcT + (size_t)n0*256, SMEM, acc);

  int wave = threadIdx.x >> 6, lane = threadIdx.x & 63;
  int lr = lane & 15, lg = lane >> 4;
  int wr = wave >> 1, wc = wave & 1;
  short (*T)[264] = (short(*)[264])SMEM;      // 32x264 = 8448 shorts <= 16384
#pragma unroll
  for (int c = 0; c < 4; c++) {
    __syncthreads();
    if (wr == (c >> 1)) {
#pragma unroll
      for (int i = 0; i < 2; i++) {
        int mi = (c & 1)*2 + i;
#pragma unroll
        for (int ni = 0; ni < 4; ni++)
#pragma unroll
          for (int r = 0; r < 4; r++) {
            int mm = i*16 + lg*4 + r;
            int nn = wc*64 + ni*16 + lr;
            T[mm][nn] = f2bf(acc[mi][ni][r] + biasc[n0 + nn]);
          }
      }
    }
    __syncthreads();
    int m0h = m0 + c*32;
    int ai = m0h / 160, bj0 = m0h % 160;      // 32 | m0h, 160 = 5*32 -> never crosses
    if (part == 2) {
      // Vin [j=ai][h][d][k=bj]: thread = (c2, half); pack 16 k-contiguous = 32B
      int c2 = threadIdx.x & 127, half = threadIdx.x >> 7;
      int pcol = (nt & 1)*128 + c2;
      int d = pcol >> 3, h = pcol & 7;
      short vals[16];
#pragma unroll
      for (int m = 0; m < 16; m++) vals[m] = T[half*16 + m][c2];
      short* dst = Vin + ((size_t)(ai*8 + h)*32 + d)*160 + bj0 + half*16;
#pragma unroll
      for (int q = 0; q < 2; q++) *(bhalf8*)(dst + q*8) = *(const bhalf8*)(vals + q*8);
    } else {
      // Q/K: thread = (m, h); pack 16 d = 32B
      int m = threadIdx.x >> 3, h = threadIdx.x & 7;
      int bj = bj0 + m;
      short vals[16];
#pragma unroll
      for (int dd = 0; dd < 16; dd++) vals[dd] = T[m][h + dd*8];
      int d0 = (nt & 1) * 16;
      short* dst;
      if (part == 0)      dst = Qin  + ((size_t)(bj*8 + h)*160 + ai)*32 + d0;
      else if (part == 1) dst = Kin  + ((size_t)(ai*8 + h)*160 + bj)*32 + d0;
      else if (part == 3) dst = Qout + ((size_t)(bj*8 + h)*160 + ai)*32 + d0;
      else                dst = Kout + ((size_t)(bj*8 + h)*160 + ai)*32 + d0;
#pragma unroll
      for (int q = 0; q < 2; q++) *(bhalf8*)(dst + q*8) = *(const bhalf8*)(vals + q*8);
    }
  }
}

// ---------------- Vout (col-major m-tiles) + E/G, direct-load path ----------------
// grid (2, 800): x==0 -> Vout 32-row col-major tile y; x==1 -> E/G 32-row tile y
__global__ __launch_bounds__(256) void voutEG_kernel(
    const short* __restrict__ eln, const short* __restrict__ WcT,
    const float* __restrict__ biasc,
    short* __restrict__ Vout,
    float* __restrict__ Ein, float* __restrict__ Gin,
    float* __restrict__ Eout, float* __restrict__ Gout) {
  int wave = threadIdx.x >> 6, lane = threadIdx.x & 63;
  int lr = lane & 15, lg = lane >> 4;
  __shared__ short T[32][264];

  if (blockIdx.x == 0) {
    int n2 = blockIdx.y / 5; int bn1 = (blockIdx.y % 5) * 32;
    int m0 = bn1*160 + n2;
    const short* a0p = eln + (m0 + lr*160) * 256;
    const short* a1p = eln + (m0 + (16 + lr)*160) * 256;
    int nb = 5 * 256;
    int wn = nb + wave * 64;
    const short* b0p = WcT + (wn + lr) * 256;
    floatx4 acc[2][4] = {};
    for (int kk = 0; kk < 256; kk += 32) {
      int ko = kk + lg*8;
      bhalf8 a0 = *(const bhalf8*)(a0p + ko);
      bhalf8 a1 = *(const bhalf8*)(a1p + ko);
#pragma unroll
      for (int f = 0; f < 4; f++) {
        bhalf8 b = *(const bhalf8*)(b0p + f*16*256 + ko);
        acc[0][f] = __builtin_amdgcn_mfma_f32_16x16x32_bf16(a0, b, acc[0][f], 0, 0, 0);
        acc[1][f] = __builtin_amdgcn_mfma_f32_16x16x32_bf16(a1, b, acc[1][f], 0, 0, 0);
      }
    }
#pragma unroll
    for (int i = 0; i < 2; i++)
#pragma unroll
      for (int f = 0; f < 4; f++)
#pragma unroll
        for (int r = 0; r < 4; r++) {
          int mm = i*16 + lg*4 + r;
          int nn = wave*64 + f*16 + lr;
          T[mm][nn] = f2bf(acc[i][f][r] + biasc[nb + nn]);
        }
    __syncthreads();
    int c = threadIdx.x, h = c & 7, d = c >> 3;
    short vals[32];
#pragma unroll
    for (int m = 0; m < 32; m++) vals[m] = T[m][c];
    short* dst = Vout + ((size_t)(n2*8 + h)*32 + d)*160 + bn1;   // [j=n2][h][d][k=n1]
#pragma unroll
    for (int q = 0; q < 4; q++) *(bhalf8*)(dst + q*8) = *(const bhalf8*)(vals + q*8);
  } else {
    // E/G tile: 32 m x 64 n (n = 1536..1599)
    int m0 = blockIdx.y * 32;
    int wn = 1536 + wave * 16;
    const short* a0p = eln + (m0 + lr) * 256;
    const short* a1p = eln + (m0 + 16 + lr) * 256;
    const short* b0p = WcT + (wn + lr) * 256;
    floatx4 acc[2] = {};
    for (int kk = 0; kk < 256; kk += 32) {
      int ko = kk + lg*8;
      bhalf8 a0 = *(const bhalf8*)(a0p + ko);
      bhalf8 a1 = *(const bhalf8*)(a1p + ko);
      bhalf8 b  = *(const bhalf8*)(b0p + ko);
      acc[0] = __builtin_amdgcn_mfma_f32_16x16x32_bf16(a0, b, acc[0], 0, 0, 0);
      acc[1] = __builtin_amdgcn_mfma_f32_16x16x32_bf16(a1, b, acc[1], 0, 0, 0);
    }
    int n = wn + lr;
    if (n < 1568) {
      int t = n - 1536;
      float* dst = (t < 8) ? Ein : (t < 16) ? Gin : (t < 24) ? Eout : Gout;
#pragma unroll
      for (int i = 0; i < 2; i++)
#pragma unroll
        for (int r = 0; r < 4; r++) {
          int m = m0 + i*16 + lg*4 + r;
          dst[m*8 + (t & 7)] = acc[i][r] + biasc[n];
        }
    }
  }
}

// ---------------- EMS/GSS precompute (bf16): [br*8+h][i][k] ----------------
__global__ __launch_bounds__(256) void ems_kernel(
    const float* __restrict__ Ein, const float* __restrict__ Gin,
    const float* __restrict__ Eout, const float* __restrict__ Gout,
    const float* __restrict__ mask,
    unsigned short* __restrict__ EMS, unsigned short* __restrict__ GSS) {
  int idx = blockIdx.x * 256 + threadIdx.x;   // 16*25600 total
  if (idx >= 16 * 25600) return;
  int hb = idx / 25600;
  int rem = idx - hb * 25600;
  int i = rem / 160, k = rem - i * 160;
  int br = hb >> 3, h = hb & 7;
  int src = br ? ((k*160 + i)*8 + h) : ((i*160 + k)*8 + h);
  float ev = br ? Eout[src] : Ein[src];
  float gv = br ? Gout[src] : Gin[src];
  float mv = mask[src];
  EMS[idx] = (unsigned short)f2bf(ev + mv);
  GSS[idx] = (unsigned short)f2bf(1.f / (1.f + __expf(-(gv + mv))));
}

// ---------------- fused attention v2: wave-independent, S^T via mfma(K,Q) ----------------
__global__ __launch_bounds__(256) void attn_kernel(
    const short* __restrict__ Qin, const short* __restrict__ Kin, const short* __restrict__ Vin,
    const short* __restrict__ Qout, const short* __restrict__ Kout, const short* __restrict__ Vout,
    const unsigned short* __restrict__ EMS, const unsigned short* __restrict__ GSS,
    short* __restrict__ Va) {
  int wave = threadIdx.x >> 6, lane = threadIdx.x & 63;
  int g = blockIdx.x * 4 + wave;          // 0..12799
  int pair = g % 5;
  int u = g / 5;
  int h = u & 7;
  int v = u >> 3;
  int br = v & 1;
  int j = v >> 1;
  int lr = lane & 15, lg = lane >> 4;
  const short* Qg = (br ? Qout : Qin) + (j*8 + h) * 5120;   // [i][d]
  const short* Kg = (br ? Kout : Kin) + (j*8 + h) * 5120;   // [k][d]
  const short* Vg = (br ? Vout : Vin) + (j*8 + h) * 5120;   // [d][k]
  const unsigned short* EMh = EMS + (br*8 + h) * 25600;     // [i][k]
  const unsigned short* GSh = GSS + (br*8 + h) * 25600;
  __shared__ short Ps[4][16][PSW];

  bhalf8 kf[10];
#pragma unroll
  for (int kt = 0; kt < 10; kt++)
    kf[kt] = *(const bhalf8*)(Kg + (kt*16 + lr)*32 + lg*8);

  const floatx4 zero = {0.f, 0.f, 0.f, 0.f};
  int hh = br*8 + h;
#pragma unroll
  for (int qi = 0; qi < 2; qi++) {
    int qt = pair*2 + qi;
    int i0 = qt*16;
    bhalf8 qf = *(const bhalf8*)(Qg + (i0 + lr)*32 + lg*8);
    int erow = (i0 + lr)*160;
    floatx4 s[10];
#pragma unroll
    for (int kt = 0; kt < 10; kt++) {
      ushort4v em = *(const ushort4v*)(EMh + erow + kt*16 + lg*4);
      floatx4 c0;
      c0[0] = bf2f(em[0]); c0[1] = bf2f(em[1]); c0[2] = bf2f(em[2]); c0[3] = bf2f(em[3]);
      s[kt] = __builtin_amdgcn_mfma_f32_16x16x32_bf16(kf[kt], qf, c0, 0, 0, 0); // D[k][i]
    }
    float mx = -1e30f;
#pragma unroll
    for (int kt = 0; kt < 10; kt++)
#pragma unroll
      for (int r = 0; r < 4; r++) mx = fmaxf(mx, s[kt][r]);
    mx = fmaxf(mx, __shfl_xor(mx, 16, 64));
    mx = fmaxf(mx, __shfl_xor(mx, 32, 64));
    float sm = 0.f;
#pragma unroll
    for (int kt = 0; kt < 10; kt++)
#pragma unroll
      for (int r = 0; r < 4; r++) {
        float p = __expf(s[kt][r] - mx);
        s[kt][r] = p;
        sm += p;
      }
    sm += __shfl_xor(sm, 16, 64);
    sm += __shfl_xor(sm, 32, 64);
    float rs = 1.f / sm;
#pragma unroll
    for (int kt = 0; kt < 10; kt++) {
      ushort4v gs = *(const ushort4v*)(GSh + erow + kt*16 + lg*4);
      short4v pk;
      pk[0] = f2bf(s[kt][0] * rs * bf2f(gs[0]));
      pk[1] = f2bf(s[kt][1] * rs * bf2f(gs[1]));
      pk[2] = f2bf(s[kt][2] * rs * bf2f(gs[2]));
      pk[3] = f2bf(s[kt][3] * rs * bf2f(gs[3]));
      *(short4v*)(&Ps[wave][lr][kt*16 + lg*4]) = pk;
    }
    floatx4 accv0 = zero, accv1 = zero;
#pragma unroll
    for (int kc = 0; kc < 5; kc++) {
      bhalf8 ap  = *(const bhalf8*)(&Ps[wave][lr][kc*32 + lg*8]);
      bhalf8 bv0 = *(const bhalf8*)(Vg + lr*160 + kc*32 + lg*8);
      bhalf8 bv1 = *(const bhalf8*)(Vg + (16 + lr)*160 + kc*32 + lg*8);
      accv0 = __builtin_amdgcn_mfma_f32_16x16x32_bf16(ap, bv0, accv0, 0, 0, 0);
      accv1 = __builtin_amdgcn_mfma_f32_16x16x32_bf16(ap, bv1, accv1, 0, 0, 0);
    }
#pragma unroll
    for (int r = 0; r < 4; r++) {
      int i = i0 + lg*4 + r;
      short* vp = Va + ((size_t)i*160 + j)*512 + hh*32;
      vp[lr]      = f2bf(accv0[r]);
      vp[16 + lr] = f2bf(accv1[r]);
    }
  }
}

// ---------------- output projection GEMM (128x128, staged) ----------------
// grid (2, 200): x = n-tile, y = m-tile
__global__ __launch_bounds__(256) void out_gemm128_kernel(
    const short* __restrict__ Va, const short* __restrict__ WoT,
    const float* __restrict__ bo, float* __restrict__ out) {
  int n0 = blockIdx.x * 128, m0 = blockIdx.y * 128;
  __shared__ short SMEM[16384];
  floatx4 acc[4][4] = {};
  gemm128_mainloop<512>(Va + (size_t)m0*512, WoT + (size_t)n0*512, SMEM, acc);
  int wave = threadIdx.x >> 6, lane = threadIdx.x & 63;
  int lr = lane & 15, lg = lane >> 4;
  int wr = wave >> 1, wc = wave & 1;
#pragma unroll
  for (int mi = 0; mi < 4; mi++)
#pragma unroll
    for (int ni = 0; ni < 4; ni++)
#pragma unroll
      for (int r = 0; r < 4; r++) {
        int m = m0 + wr*64 + mi*16 + lg*4 + r;
        int n = n0 + wc*64 + ni*16 + lr;
        out[(size_t)m*256 + n] = acc[mi][ni][r] + bo[n];
      }
}

extern "C" void kernel_launch(void* const* d_in, const int* in_sizes, int n_in,
                              void* d_out, int out_size, void* d_ws, size_t ws_size,
                              hipStream_t stream) {
  const float* e        = (const float*)d_in[0];
  const float* mask     = (const float*)d_in[1];
  const float* ln_g     = (const float*)d_in[2];
  const float* ln_b     = (const float*)d_in[3];
  const float* Wqkv_in  = (const float*)d_in[4];
  const float* bqkv_in  = (const float*)d_in[5];
  const float* Weg_in   = (const float*)d_in[6];
  const float* beg_in   = (const float*)d_in[7];
  const float* Wqkv_out = (const float*)d_in[8];
  const float* bqkv_out = (const float*)d_in[9];
  const float* Weg_out  = (const float*)d_in[10];
  const float* beg_out  = (const float*)d_in[11];
  const float* Wo       = (const float*)d_in[12];
  const float* bo       = (const float*)d_in[13];
  float* out = (float*)d_out;

  char* ws = (char*)d_ws;
  size_t off = 0;
  auto alloc = [&](size_t bytes) -> void* {
    void* p = ws + off;
    off += (bytes + 255) & ~(size_t)255;
    return p;
  };
  short* eln   = (short*)alloc((size_t)MROWS*256*2);
  short* WcT   = (short*)alloc((size_t)NC1*256*2);
  float* biasc = (float*)alloc((size_t)NC1*4);
  short* WoT   = (short*)alloc((size_t)256*512*2);
  short* Qin   = (short*)alloc((size_t)160*8*160*32*2);
  short* Kin   = (short*)alloc((size_t)160*8*160*32*2);
  short* Vin   = (short*)alloc((size_t)160*8*160*32*2);
  short* Qout  = (short*)alloc((size_t)160*8*160*32*2);
  short* Kout  = (short*)alloc((size_t)160*8*160*32*2);
  short* Vout  = (short*)alloc((size_t)160*8*160*32*2);
  float* Ein   = (float*)alloc((size_t)160*160*8*4);
  float* Gin   = (float*)alloc((size_t)160*160*8*4);
  float* Eout  = (float*)alloc((size_t)160*160*8*4);
  float* Gout  = (float*)alloc((size_t)160*160*8*4);
  unsigned short* EMS = (unsigned short*)alloc((size_t)16*25600*2);
  unsigned short* GSS = (unsigned short*)alloc((size_t)16*25600*2);
  short* Vabuf = (short*)alloc((size_t)MROWS*512*2);

  prep_kernel<<<2112, 256, 0, stream>>>(Wqkv_in, bqkv_in, Weg_in, beg_in,
                                        Wqkv_out, bqkv_out, Weg_out, beg_out,
                                        Wo, WcT, biasc, WoT);
  ln_kernel<<<6400, 256, 0, stream>>>(e, ln_g, ln_b, eln);
  qkv_gemm128_kernel<<<dim3(10, 200), 256, 0, stream>>>(eln, WcT, biasc,
      Qin, Kin, Vin, Qout, Kout);
  voutEG_kernel<<<dim3(2, 800), 256, 0, stream>>>(eln, WcT, biasc,
      Vout, Ein, Gin, Eout, Gout);
  ems_kernel<<<1600, 256, 0, stream>>>(Ein, Gin, Eout, Gout, mask, EMS, GSS);
  attn_kernel<<<3200, 256, 0, stream>>>(Qin, Kin, Vin, Qout, Kout, Vout,
      EMS, GSS, Vabuf);
  out_gemm128_kernel<<<dim3(2, 200), 256, 0, stream>>>(Vabuf, WoT, bo, out);
}